// Round 13
// baseline (320.044 us; speedup 1.0000x reference)
//
#include <hip/hip_runtime.h>

#define S_LEN 2048
#define NBATCH 2
#define DIMSZ 2048
#define NH 32
#define NKV 8
#define HD 64
#define QKV_N 3072
#define NTOK 4096  // NBATCH * S_LEN

typedef __attribute__((ext_vector_type(8))) short bf16x8;
typedef __attribute__((ext_vector_type(4))) short bf16x4;
typedef __attribute__((ext_vector_type(4))) float f32x4;

#define QSCALE 0.18033688011112042f  // (1/sqrt(64)) * log2(e)

__device__ __forceinline__ float bf2f(unsigned short u) {
    union { unsigned int i; float f; } v; v.i = ((unsigned int)u) << 16; return v.f;
}
__device__ __forceinline__ unsigned short f2bf(float f) {
    union { float f; unsigned int i; } v; v.f = f;
    unsigned int r = v.i + 0x7FFFu + ((v.i >> 16) & 1u);  // RNE
    return (unsigned short)(r >> 16);
}
// single-instruction 2^x (v_exp_f32 computes exp2)
__device__ __forceinline__ float exp2_fast(float x) {
    float r; asm("v_exp_f32 %0, %1" : "=v"(r) : "v"(x)); return r;
}
// pack two f32 -> one dword of 2x bf16 (lo=a, hi=b), hardware RNE
__device__ __forceinline__ unsigned int cvt_pk_bf16(float a, float b) {
    unsigned int r;
    asm("v_cvt_pk_bf16_f32 %0, %1, %2" : "=v"(r) : "v"(a), "v"(b));
    return r;
}

// async global->LDS, 16 B per lane; lds ptr must be wave-uniform base
__device__ __forceinline__ void gld_lds16(const unsigned short* g, short* l) {
    __builtin_amdgcn_global_load_lds(
        (const __attribute__((address_space(1))) unsigned int*)g,
        (__attribute__((address_space(3))) unsigned int*)l, 16, 0, 0);
}

// ---------------------------------------------------------------------------
// fp32 -> bf16 elementwise convert, 8 elems/thread; TWO arrays in one launch
// ---------------------------------------------------------------------------
__global__ __launch_bounds__(256) void convert_bf16_2(
    const float* __restrict__ a, unsigned short* __restrict__ da,
    const float* __restrict__ b, unsigned short* __restrict__ db, int ablk)
{
    const float* src;
    unsigned short* dst;
    long base;
    if ((int)blockIdx.x < ablk) { src = a; dst = da; base = (long)blockIdx.x; }
    else                        { src = b; dst = db; base = (long)blockIdx.x - ablk; }
    const long i = (base * 256 + threadIdx.x) * 8;
    float4 x = *(const float4*)(src + i);
    float4 y = *(const float4*)(src + i + 4);
    union { uint4 u; unsigned short s[8]; } o;
    o.s[0] = f2bf(x.x); o.s[1] = f2bf(x.y); o.s[2] = f2bf(x.z); o.s[3] = f2bf(x.w);
    o.s[4] = f2bf(y.x); o.s[5] = f2bf(y.y); o.s[6] = f2bf(y.z); o.s[7] = f2bf(y.w);
    *(uint4*)(dst + i) = o.u;
}

// ---------------------------------------------------------------------------
// QKV GEMM, 256x256 tile, BK=64, 512 threads / 8 waves (2M x 4N), wave
// output 128x64.  OVERLAPPED STAGING (T3 minimum recipe): prefetch of K-tile
// t+1 issued via global_load_lds BEFORE computing tile t; ONE barrier per
// K-tile (its implicit vmcnt(0) drains the prefetch).  Double-buffered
// 128 KB LDS.  XOR granule swizzle both ways (verified bank-conflict-0).
// Epilogue: bf16 scatter to split Q/K/V (wave's 64 cols = one slot).
// XCD-aware block swizzle (grid 192 %8==0).
// ---------------------------------------------------------------------------
__global__ __launch_bounds__(512, 2) void gemm_qkv_256(
    const unsigned short* __restrict__ A, const unsigned short* __restrict__ Bt,
    unsigned short* __restrict__ Qb, unsigned short* __restrict__ Kb,
    unsigned short* __restrict__ Vb, int M, int N, int K)
{
    __shared__ __align__(16) short As[2][256 * 64];  // [buf][row][k] swizzled
    __shared__ __align__(16) short Bs[2][256 * 64];

    const int tid = threadIdx.x;
    const int lane = tid & 63;
    const int wid = tid >> 6;          // 0..7
    const int quad = lane >> 4;
    const int l16 = lane & 15;
    const int wr = wid >> 2;           // 0..1 (M)
    const int wc = wid & 3;            // 0..3 (N)

    // XCD swizzle
    const int nwg = gridDim.x * gridDim.y;   // 192
    const int lin = blockIdx.y * gridDim.x + blockIdx.x;
    const int cpx = nwg >> 3;
    const int swz = (lin & 7) * cpx + (lin >> 3);
    const int bx = swz % gridDim.x;
    const int by = swz / gridDim.x;

    const int m0 = by * 256;
    const int n0 = bx * 256;

    f32x4 acc[8][4] = {};

    // staging addressing (verified pattern): 8 lanes/row, 16B granule,
    // global source granule pre-swizzled so LDS can be written linearly
    const int srow8 = lane >> 3;                  // 0..7
    const int scol8 = ((lane & 7) ^ srow8) * 8;   // swizzled granule (shorts)
    const unsigned short* Ag = A + (long)(m0 + srow8) * K + scol8;
    const unsigned short* Bg = Bt + (long)(n0 + srow8) * K + scol8;
    const int gsw = l16 & 7;                      // read-side XOR key

    const int nt = K / 64;

    // prologue: stage tile 0 into buf 0
#pragma unroll
    for (int bc = 0; bc < 4; ++bc) {
        const int blk = wid + bc * 8;             // 0..31 (8-row blocks)
        gld_lds16(Ag + (long)(blk * 8) * K, &As[0][blk * 512]);
        gld_lds16(Bg + (long)(blk * 8) * K, &Bs[0][blk * 512]);
    }
    __syncthreads();

    int cur = 0;
    for (int t = 0; t < nt; ++t) {
        // issue prefetch of tile t+1 into the other buffer (async; overlaps
        // the 64-MFMA compute below; drained by the barrier at loop end)
        if (t + 1 < nt) {
            const long k0 = (long)(t + 1) * 64;
#pragma unroll
            for (int bc = 0; bc < 4; ++bc) {
                const int blk = wid + bc * 8;
                gld_lds16(Ag + (long)(blk * 8) * K + k0, &As[cur ^ 1][blk * 512]);
                gld_lds16(Bg + (long)(blk * 8) * K + k0, &Bs[cur ^ 1][blk * 512]);
            }
        }

        // compute tile t from buf[cur]
        const short* Asc = As[cur];
        const short* Bsc = Bs[cur];
        __builtin_amdgcn_s_setprio(1);
#pragma unroll
        for (int ko = 0; ko < 2; ++ko) {
            const int ga = ((quad + ko * 4) ^ gsw) * 8;
            bf16x8 bf[4];
#pragma unroll
            for (int tn = 0; tn < 4; ++tn)
                bf[tn] = *(const bf16x8*)&Bsc[(wc * 64 + tn * 16 + l16) * 64 + ga];
#pragma unroll
            for (int rt = 0; rt < 8; ++rt) {
                bf16x8 af = *(const bf16x8*)&Asc[(wr * 128 + rt * 16 + l16) * 64 + ga];
#pragma unroll
                for (int tn = 0; tn < 4; ++tn)
                    acc[rt][tn] = __builtin_amdgcn_mfma_f32_16x16x32_bf16(af, bf[tn], acc[rt][tn], 0, 0, 0);
            }
        }
        __builtin_amdgcn_s_setprio(0);

        __syncthreads();   // drains prefetch (vmcnt 0) + all lgkm; buf swap safe
        cur ^= 1;
    }

    // epilogue: scatter to Q/K/V (wave's 64 cols = one slot, wave-uniform)
    const int slot = (n0 + wc * 64) >> 6;  // 0..47
#pragma unroll
    for (int rt = 0; rt < 8; ++rt)
#pragma unroll
        for (int i = 0; i < 4; ++i) {
            const int row = m0 + wr * 128 + rt * 16 + quad * 4 + i;
            const int b = row >> 11, s = row & 2047;
            unsigned short* base;
            if (slot < 32)      base = Qb + ((long)(b * NH + slot) * S_LEN + s) * HD;
            else if (slot < 40) base = Kb + ((long)(b * NKV + (slot - 32)) * S_LEN + s) * HD;
            else                base = Vb + ((long)(b * NKV + (slot - 40)) * S_LEN + s) * HD;
#pragma unroll
            for (int tn = 0; tn < 4; ++tn)
                base[tn * 16 + l16] = f2bf(acc[rt][tn][i]);
        }
}

// ---------------------------------------------------------------------------
// BMx128 GEMM, BK=64, bank-conflict-free (verified SQ_LDS_BANK_CONFLICT=0).
// EPI 0: fp32 C.  EPI 1: bf16 scatter to split Q/K/V.
// XCD-aware block swizzle (T1): grids are %8==0, simple bijective remap.
// ---------------------------------------------------------------------------
template <int EPI, int BM>
__global__ __launch_bounds__(256) void gemm_bt128(
    const unsigned short* __restrict__ A, const unsigned short* __restrict__ Bt,
    float* __restrict__ C,
    unsigned short* __restrict__ Qb, unsigned short* __restrict__ Kb,
    unsigned short* __restrict__ Vb, int M, int N, int K)
{
    constexpr int TM = BM / 32;                   // row-tiles per wave
    __shared__ __align__(16) short As[BM * 64];   // [row][k], swizzled granules
    __shared__ __align__(16) short Bs[128 * 64];

    const int tid = threadIdx.x;
    const int lane = tid & 63;
    const int wid = tid >> 6;
    const int quad = lane >> 4;
    const int l16 = lane & 15;

    // XCD swizzle: each XCD gets a contiguous chunk of the linear grid
    const int nwg = gridDim.x * gridDim.y;
    const int lin = blockIdx.y * gridDim.x + blockIdx.x;
    const int cpx = nwg >> 3;                      // nwg % 8 == 0 for our grids
    const int swz = (lin & 7) * cpx + (lin >> 3);
    const int bx = swz % gridDim.x;
    const int by = swz / gridDim.x;

    const int m0 = by * BM;
    const int n0 = bx * 128;
    const int wm = (wid & 1) * (BM / 2);
    const int wn = (wid >> 1) * 64;

    f32x4 acc[TM][4] = {};

    // staging: 8 lanes per row, 16B granule each; source granule pre-swizzled
    const int srow8 = lane >> 3;                  // 0..7 (row within 8-row blk)
    const int scol8 = ((lane & 7) ^ srow8) * 8;   // swizzled granule (shorts)
    const unsigned short* Ag = A + (long)(m0 + srow8) * K + scol8;
    const unsigned short* Bg = Bt + (long)(n0 + srow8) * K + scol8;
    const int gsw = l16 & 7;                      // read-side XOR key

    for (int k0 = 0; k0 < K; k0 += 64) {
        __syncthreads();
#pragma unroll
        for (int bc = 0; bc < 4; ++bc) {
            const int blk = wid + bc * 4;         // 0..15 (8-row blocks)
            if (bc < BM / 32)
                gld_lds16(Ag + (long)(blk * 8) * K + k0, &As[blk * 512]);
            gld_lds16(Bg + (long)(blk * 8) * K + k0, &Bs[blk * 512]);
        }
        __syncthreads();

#pragma unroll
        for (int ko = 0; ko < 2; ++ko) {
            const int ga = ((quad + ko * 4) ^ gsw) * 8;  // swizzled frag granule
            bf16x8 af[TM], bf[4];
#pragma unroll
            for (int t = 0; t < TM; ++t)
                af[t] = *(const bf16x8*)&As[(wm + t * 16 + l16) * 64 + ga];
#pragma unroll
            for (int t = 0; t < 4; ++t)
                bf[t] = *(const bf16x8*)&Bs[(wn + t * 16 + l16) * 64 + ga];
#pragma unroll
            for (int tm = 0; tm < TM; ++tm)
#pragma unroll
                for (int tn = 0; tn < 4; ++tn)
                    acc[tm][tn] = __builtin_amdgcn_mfma_f32_16x16x32_bf16(af[tm], bf[tn], acc[tm][tn], 0, 0, 0);
        }
    }

    if (EPI == 0) {
#pragma unroll
        for (int tm = 0; tm < TM; ++tm)
#pragma unroll
            for (int i = 0; i < 4; ++i) {
                const int row = m0 + wm + tm * 16 + quad * 4 + i;
#pragma unroll
                for (int tn = 0; tn < 4; ++tn)
                    C[(long)row * N + n0 + wn + tn * 16 + l16] = acc[tm][tn][i];
            }
    } else {
        const int slot = (n0 + wn) >> 6;  // wave-uniform: 0..47
#pragma unroll
        for (int tm = 0; tm < TM; ++tm)
#pragma unroll
            for (int i = 0; i < 4; ++i) {
                const int row = m0 + wm + tm * 16 + quad * 4 + i;
                const int b = row >> 11, s = row & 2047;
                unsigned short* base;
                if (slot < 32)      base = Qb + ((long)(b * NH + slot) * S_LEN + s) * HD;
                else if (slot < 40) base = Kb + ((long)(b * NKV + (slot - 32)) * S_LEN + s) * HD;
                else                base = Vb + ((long)(b * NKV + (slot - 40)) * S_LEN + s) * HD;
#pragma unroll
                for (int tn = 0; tn < 4; ++tn)
                    base[tn * 16 + l16] = f2bf(acc[tm][tn][i]);
            }
    }
}

// ---------------------------------------------------------------------------
// PREP kernel (fast path): three independent small jobs in ONE launch:
//   [0, 512)        V -> Vt (kv-permuted transpose)
//   [512, 10752)    LN+RoPE in-place on Q and K
//   [10752, 14848)  wo^T -> bf16 (Wot)
// ---------------------------------------------------------------------------
__global__ __launch_bounds__(256) void prep_kernel(
    const unsigned short* __restrict__ V, unsigned short* __restrict__ Vt,
    unsigned short* __restrict__ Qb, unsigned short* __restrict__ Kb,
    const float* __restrict__ qg, const float* __restrict__ qb,
    const float* __restrict__ kg, const float* __restrict__ kb,
    const float* __restrict__ fcos, const float* __restrict__ fsin,
    const float* __restrict__ wo, unsigned short* __restrict__ Wot)
{
    __shared__ __align__(16) unsigned short shbuf[64 * 72];
    const int bid = blockIdx.x;
    const int tid = threadIdx.x;

    if (bid < 512) {
        unsigned short (*tile)[72] = (unsigned short(*)[72])shbuf;
        const int bk = bid >> 5;
        const int s0 = (bid & 31) * 64;
        const int r = tid >> 2, c0 = (tid & 3) * 16;

        const unsigned short* src = V + ((long)bk * S_LEN + s0 + r) * HD + c0;
        *(uint4*)&tile[r][c0]     = *(const uint4*)src;
        *(uint4*)&tile[r][c0 + 8] = *(const uint4*)(src + 8);
        __syncthreads();

        union { uint4 u[2]; unsigned short s[16]; } o;
        const int q = tid & 3;
#pragma unroll
        for (int j = 0; j < 16; ++j) {
            const int t = 2 * (j >> 3) + ((j >> 2) & 1);
            const int kv = t * 16 + q * 4 + (j & 3);
            o.s[j] = tile[kv][r];
        }
        unsigned short* dst = Vt + ((long)bk * HD + r) * S_LEN + s0 + c0;
        *(uint4*)dst       = o.u[0];
        *(uint4*)(dst + 8) = o.u[1];
    } else if (bid < 10752) {
        const int l16 = tid & 15;
        const int rgrp = tid >> 4;
        const int row = (bid - 512) * 16 + rgrp;
        const int token = row / 40;
        const int slot = row - token * 40;
        const int b = token >> 11;
        const int s = token & 2047;
        const bool isq = slot < 32;

        unsigned short* base = isq
            ? Qb + ((long)(b * NH + slot) * S_LEN + s) * HD
            : Kb + ((long)(b * NKV + (slot - 32)) * S_LEN + s) * HD;

        union { ushort4 u; unsigned short h[4]; } in;
        in.u = *(const ushort4*)(base + l16 * 4);
        float f0 = bf2f(in.h[0]), f1 = bf2f(in.h[1]);
        float f2 = bf2f(in.h[2]), f3 = bf2f(in.h[3]);

        float sum = (f0 + f1) + (f2 + f3);
#pragma unroll
        for (int off = 1; off < 16; off <<= 1) sum += __shfl_xor(sum, off);
        const float mu = sum * (1.0f / 64.0f);
        const float d0v = f0 - mu, d1v = f1 - mu, d2v = f2 - mu, d3v = f3 - mu;
        float vs = (d0v * d0v + d1v * d1v) + (d2v * d2v + d3v * d3v);
#pragma unroll
        for (int off = 1; off < 16; off <<= 1) vs += __shfl_xor(vs, off);
        const float rs = rsqrtf(vs * (1.0f / 64.0f) + 1e-5f);

        const float4 g  = *(const float4*)((isq ? qg : kg) + l16 * 4);
        const float4 be = *(const float4*)((isq ? qb : kb) + l16 * 4);
        float n0 = d0v * rs * g.x + be.x;
        float n1 = d1v * rs * g.y + be.y;
        float n2 = d2v * rs * g.z + be.z;
        float n3 = d3v * rs * g.w + be.w;

        const float2 cs = *(const float2*)(fcos + s * 32 + l16 * 2);
        const float2 sn = *(const float2*)(fsin + s * 32 + l16 * 2);
        float o0 = n0 * cs.x - n1 * sn.x;
        float o1 = n0 * sn.x + n1 * cs.x;
        float o2 = n2 * cs.y - n3 * sn.y;
        float o3 = n2 * sn.y + n3 * cs.y;

        if (isq) { o0 *= QSCALE; o1 *= QSCALE; o2 *= QSCALE; o3 *= QSCALE; }

        union { ushort4 u; unsigned short h[4]; } out;
        out.h[0] = f2bf(o0); out.h[1] = f2bf(o1);
        out.h[2] = f2bf(o2); out.h[3] = f2bf(o3);
        *(ushort4*)(base + l16 * 4) = out.u;
    } else {
        unsigned short (*tile)[33] = (unsigned short(*)[33])shbuf;
        const int b2 = bid - 10752;
        const int bx = b2 & 63, by = b2 >> 6;
        const int tx = tid & 31;
        const int ty = tid >> 5;
        const int x = bx * 32 + tx;
        const int y0 = by * 32;
        for (int j = ty; j < 32; j += 8)
            tile[j][tx] = f2bf(wo[(long)(y0 + j) * DIMSZ + x]);
        __syncthreads();
        const int x2 = by * 32 + tx;
        const int y2 = bx * 32;
        for (int j = ty; j < 32; j += 8)
            Wot[(long)(y2 + j) * DIMSZ + x2] = tile[tx][j];
    }
}

// ---------------------------------------------------------------------------
// Fallback QKV GEMM (fp32 in, register-convert staging, 64x64).
// ---------------------------------------------------------------------------
__global__ __launch_bounds__(256) void gemm_qkv_mfma(
    const float* __restrict__ A, const float* __restrict__ Bt,
    unsigned short* __restrict__ Qb, unsigned short* __restrict__ Kb,
    unsigned short* __restrict__ Vb, int M, int N, int K)
{
    const int LW = 40;
    __shared__ __align__(16) short As[64 * LW];
    __shared__ __align__(16) short Bs[64 * LW];

    const int tid = threadIdx.x;
    const int lane = tid & 63;
    const int wid = tid >> 6;
    const int quad = lane >> 4;
    const int l16 = lane & 15;

    const int m0 = blockIdx.y * 64;
    const int n0 = blockIdx.x * 64;
    const int wm = (wid >> 1) * 32;
    const int wn = (wid & 1) * 32;

    f32x4 acc[2][2] = {};

    const int srow = tid >> 2;
    const int scol = (tid & 3) * 8;

    const float* Ag = A + (long)(m0 + srow) * K + scol;
    const float* Bg = Bt + (long)(n0 + srow) * K + scol;
    short* da = &As[srow * LW + scol];
    short* db = &Bs[srow * LW + scol];

    for (int k0 = 0; k0 < K; k0 += 32) {
        __syncthreads();
        float4 a0 = *(const float4*)(Ag + k0), a1 = *(const float4*)(Ag + k0 + 4);
        float4 b0 = *(const float4*)(Bg + k0), b1 = *(const float4*)(Bg + k0 + 4);
        union { uint4 u; short s[8]; } pa, pb;
        pa.s[0] = (short)f2bf(a0.x); pa.s[1] = (short)f2bf(a0.y);
        pa.s[2] = (short)f2bf(a0.z); pa.s[3] = (short)f2bf(a0.w);
        pa.s[4] = (short)f2bf(a1.x); pa.s[5] = (short)f2bf(a1.y);
        pa.s[6] = (short)f2bf(a1.z); pa.s[7] = (short)f2bf(a1.w);
        pb.s[0] = (short)f2bf(b0.x); pb.s[1] = (short)f2bf(b0.y);
        pb.s[2] = (short)f2bf(b0.z); pb.s[3] = (short)f2bf(b0.w);
        pb.s[4] = (short)f2bf(b1.x); pb.s[5] = (short)f2bf(b1.y);
        pb.s[6] = (short)f2bf(b1.z); pb.s[7] = (short)f2bf(b1.w);
        *(uint4*)da = pa.u;
        *(uint4*)db = pb.u;
        __syncthreads();

        bf16x8 bfr[2];
#pragma unroll
        for (int tc = 0; tc < 2; ++tc)
            bfr[tc] = *(const bf16x8*)&Bs[(wn + tc * 16 + l16) * LW + quad * 8];
#pragma unroll
        for (int tr = 0; tr < 2; ++tr) {
            bf16x8 a = *(const bf16x8*)&As[(wm + tr * 16 + l16) * LW + quad * 8];
#pragma unroll
            for (int tc = 0; tc < 2; ++tc)
                acc[tr][tc] = __builtin_amdgcn_mfma_f32_16x16x32_bf16(a, bfr[tc], acc[tr][tc], 0, 0, 0);
        }
    }

    const int slot = n0 >> 6;
#pragma unroll
    for (int tr = 0; tr < 2; ++tr)
#pragma unroll
        for (int tc = 0; tc < 2; ++tc)
#pragma unroll
            for (int i = 0; i < 4; ++i) {
                const int row = m0 + wm + tr * 16 + quad * 4 + i;
                const int d = wn + tc * 16 + l16;
                const int b = row >> 11, s = row & 2047;
                unsigned short v = f2bf(acc[tr][tc][i]);
                if (slot < 32)
                    Qb[((long)(b * NH + slot) * S_LEN + s) * HD + d] = v;
                else if (slot < 40)
                    Kb[((long)(b * NKV + (slot - 32)) * S_LEN + s) * HD + d] = v;
                else
                    Vb[((long)(b * NKV + (slot - 40)) * S_LEN + s) * HD + d] = v;
            }
}

// ---------------------------------------------------------------------------
// Fallback: in-place LayerNorm(64) + RoPE on Q and K.
// ---------------------------------------------------------------------------
__global__ __launch_bounds__(256) void lnrope_kernel(
    unsigned short* __restrict__ Qb, unsigned short* __restrict__ Kb,
    const float* __restrict__ qg, const float* __restrict__ qb,
    const float* __restrict__ kg, const float* __restrict__ kb,
    const float* __restrict__ fcos, const float* __restrict__ fsin)
{
    const int tid = threadIdx.x;
    const int l16 = tid & 15;
    const int rgrp = tid >> 4;
    const int row = blockIdx.x * 16 + rgrp;
    const int token = row / 40;
    const int slot = row - token * 40;
    const int b = token >> 11;
    const int s = token & 2047;
    const bool isq = slot < 32;

    unsigned short* base = isq
        ? Qb + ((long)(b * NH + slot) * S_LEN + s) * HD
        : Kb + ((long)(b * NKV + (slot - 32)) * S_LEN + s) * HD;

    union { ushort4 u; unsigned short h[4]; } in;
    in.u = *(const ushort4*)(base + l16 * 4);
    float f0 = bf2f(in.h[0]), f1 = bf2f(in.h[1]);
    float f2 = bf2f(in.h[2]), f3 = bf2f(in.h[3]);

    float sum = (f0 + f1) + (f2 + f3);
#pragma unroll
    for (int off = 1; off < 16; off <<= 1) sum += __shfl_xor(sum, off);
    const float mu = sum * (1.0f / 64.0f);
    const float d0v = f0 - mu, d1v = f1 - mu, d2v = f2 - mu, d3v = f3 - mu;
    float vs = (d0v * d0v + d1v * d1v) + (d2v * d2v + d3v * d3v);
#pragma unroll
    for (int off = 1; off < 16; off <<= 1) vs += __shfl_xor(vs, off);
    const float rs = rsqrtf(vs * (1.0f / 64.0f) + 1e-5f);

    const float4 g  = *(const float4*)((isq ? qg : kg) + l16 * 4);
    const float4 be = *(const float4*)((isq ? qb : kb) + l16 * 4);
    float n0 = d0v * rs * g.x + be.x;
    float n1 = d1v * rs * g.y + be.y;
    float n2 = d2v * rs * g.z + be.z;
    float n3 = d3v * rs * g.w + be.w;

    const float2 cs = *(const float2*)(fcos + s * 32 + l16 * 2);
    const float2 sn = *(const float2*)(fsin + s * 32 + l16 * 2);
    float o0 = n0 * cs.x - n1 * sn.x;
    float o1 = n0 * sn.x + n1 * cs.x;
    float o2 = n2 * cs.y - n3 * sn.y;
    float o3 = n2 * sn.y + n3 * cs.y;

    if (isq) { o0 *= QSCALE; o1 *= QSCALE; o2 *= QSCALE; o3 *= QSCALE; }

    union { ushort4 u; unsigned short h[4]; } out;
    out.h[0] = f2bf(o0); out.h[1] = f2bf(o1);
    out.h[2] = f2bf(o2); out.h[3] = f2bf(o3);
    *(ushort4*)(base + l16 * 4) = out.u;
}

// ---------------------------------------------------------------------------
// Fallback: V -> V^T in global, kv-PERMUTED within each 64-chunk.
// ---------------------------------------------------------------------------
__global__ __launch_bounds__(256) void transpose_v(
    const unsigned short* __restrict__ V, unsigned short* __restrict__ Vt)
{
    __shared__ unsigned short tile[64][72];
    const int tid = threadIdx.x;
    const int bk = blockIdx.y;
    const int s0 = blockIdx.x * 64;
    const int r = tid >> 2, c0 = (tid & 3) * 16;

    const unsigned short* src = V + ((long)bk * S_LEN + s0 + r) * HD + c0;
    *(uint4*)&tile[r][c0]     = *(const uint4*)src;
    *(uint4*)&tile[r][c0 + 8] = *(const uint4*)(src + 8);
    __syncthreads();

    union { uint4 u[2]; unsigned short s[16]; } o;
    const int q = tid & 3;
#pragma unroll
    for (int j = 0; j < 16; ++j) {
        const int t = 2 * (j >> 3) + ((j >> 2) & 1);
        const int kv = t * 16 + q * 4 + (j & 3);
        o.s[j] = tile[kv][r];
    }
    unsigned short* dst = Vt + ((long)bk * HD + r) * S_LEN + s0 + c0;
    *(uint4*)dst       = o.u[0];
    *(uint4*)(dst + 8) = o.u[1];
}

// ---------------------------------------------------------------------------
// Fallback: wo^T -> bf16, 2048x2048
// ---------------------------------------------------------------------------
__global__ __launch_bounds__(256) void transpose_wo(
    const float* __restrict__ in, unsigned short* __restrict__ out, int n)
{
    __shared__ unsigned short tile[32][33];
    const int tx = threadIdx.x & 31;
    const int ty = threadIdx.x >> 5;
    const int x = blockIdx.x * 32 + tx;
    const int y0 = blockIdx.y * 32;
    for (int j = ty; j < 32; j += 8) tile[j][tx] = f2bf(in[(long)(y0 + j) * n + x]);
    __syncthreads();
    const int x2 = blockIdx.y * 32 + tx;
    const int y2 = blockIdx.x * 32;
    for (int j = ty; j < 32; j += 8) out[(long)(y2 + j) * n + x2] = tile[tx][j];
}

// ---------------------------------------------------------------------------
// MFMA flash attention, causal (round-11 verified; unchanged).
// ---------------------------------------------------------------------------
#define KSTR 72  // LDS stride (shorts)

__global__ __launch_bounds__(512, 4) void attn_mfma(
    const unsigned short* __restrict__ Q,
    const unsigned short* __restrict__ Kin,
    const unsigned short* __restrict__ Vtg,
    unsigned short* __restrict__ Oatt)
{
    __shared__ __align__(16) short Ks[2][64 * KSTR];   // [buf][kv][hd]
    __shared__ __align__(16) short Vs[2][64 * KSTR];   // [buf][d][kv-perm]

    const int tid = threadIdx.x;
    const int lane = tid & 63;
    const int wid = tid >> 6;          // 0..7
    const int quad = lane >> 4;
    const int l16 = lane & 15;

    const int bh = blockIdx.x;
    const int b = bh >> 5, h = bh & 31, kvh = h >> 2;
    const int NY = S_LEN / 128;                 // 16 q-tiles
    const int tlo = blockIdx.y;                 // 0..7
    const int thi = (NY - 1) - tlo;             // 15..8
    const int tq = (wid >> 2) ? thi : tlo;      // this wave's q-tile
    const int w32 = tq * 128 + (wid & 3) * 32;  // this wave's 32 q-rows

    const unsigned short* Qb = Q + (long)(b * NH + h) * S_LEN * HD;
    const unsigned short* Kb = Kin + (long)(b * NKV + kvh) * S_LEN * HD;
    const unsigned short* Vtb = Vtg + (long)(b * NKV + kvh) * HD * S_LEN;

    bf16x8 qf[2][2];  // [sub][half]
#pragma unroll
    for (int s = 0; s < 2; ++s) {
        qf[s][0] = *(const bf16x8*)(Qb + (long)(w32 + s * 16 + l16) * HD + quad * 8);
        qf[s][1] = *(const bf16x8*)(Qb + (long)(w32 + s * 16 + l16) * HD + 32 + quad * 8);
    }

    f32x4 oacc[2][4] = {};
    float l_r[2] = {0.0f, 0.0f};   // per-lane partial denominators

    // staging: tid<256 -> K, tid>=256 -> V; 32B per thread
    const bool stK = tid < 256;
    const int st = stK ? tid : tid - 256;
    const int kk = st >> 2;           // row (K: kv row, V: d row)
    const int d0 = (st & 3) * 16;     // 16-short segment
    const unsigned short* gsrc = stK
        ? Kb + (long)kk * HD + d0
        : Vtb + (long)kk * S_LEN + d0;
    const long ginc = stK ? (long)64 * HD : 64;  // per-chunk advance (shorts)
    short* const lds0 = stK ? &Ks[0][kk * KSTR + d0] : &Vs[0][kk * KSTR + d0];
    short* const lds1 = stK ? &Ks[1][kk * KSTR + d0] : &Vs[1][kk * KSTR + d0];

    const int nch = 2 * thi + 2;      // hi tile defines the chunk range

    uint4 r0, r1;
    {   // prologue: chunk 0 -> regs -> buf0
        r0 = *(const uint4*)gsrc; r1 = *(const uint4*)(gsrc + 8);
        *(uint4*)lds0 = r0; *(uint4*)(lds0 + 8) = r1;
    }

    for (int c = 0; c < nch; ++c) {
        const int cur = c & 1;
        const int kbase = c * 64;
        __syncthreads();  // buf[cur] ready; all waves done reading buf[cur^1]

        // issue loads for chunk c+1 (latency hides under compute of chunk c)
        if (c + 1 < nch) {
            const unsigned short* p = gsrc + (long)(c + 1) * ginc;
            r0 = *(const uint4*)p; r1 = *(const uint4*)(p + 8);
        }

        if (kbase <= w32 + 31) {
            const bool act0 = (kbase <= w32 + 15);  // subtile 0 active?
            const short* Ksc = Ks[cur];
            const short* Vsc = Vs[cur];

            // ---- QK^T swapped, K-frags read once, shared by both subtiles:
            //      sc[s][t][r] = S[kv=kbase+16t+4*quad+r][q=qw+l16]
            f32x4 sc[2][4];
            __builtin_amdgcn_s_setprio(1);
#pragma unroll
            for (int t = 0; t < 4; ++t) {
                bf16x8 kf0 = *(const bf16x8*)&Ksc[(t * 16 + l16) * KSTR + quad * 8];
                bf16x8 kf1 = *(const bf16x8*)&Ksc[(t * 16 + l16) * KSTR + 32 + quad * 8];
#pragma unroll
                for (int s = 0; s < 2; ++s) {
                    if (s == 0 && !act0) continue;
                    f32x4 z = {};
                    z = __builtin_amdgcn_mfma_f32_16x16x32_bf16(kf0, qf[s][0], z, 0, 0, 0);
                    sc[s][t] = __builtin_amdgcn_mfma_f32_16x16x32_bf16(kf1, qf[s][1], z, 0, 0, 0);
                }
            }
            __builtin_amdgcn_s_setprio(0);

#pragma unroll
            for (int s = 0; s < 2; ++s) {
                if (s == 0 && !act0) continue;
                const int qw = w32 + s * 16;
                const bool diag = (kbase + 63 > qw);  // wave-uniform

                // ---- mask in place (diag only); exp2(-1e30) == 0 ----
                if (diag) {
                    const int rel = qw + l16 - kbase;
#pragma unroll
                    for (int t = 0; t < 4; ++t)
#pragma unroll
                        for (int r = 0; r < 4; ++r) {
                            const int kvrel = t * 16 + quad * 4 + r;
                            if (kvrel > rel) sc[s][t][r] = -1e30f;
                        }
                }

                // ---- raw exp2 (shift-invariant softmax), per-lane partial sum
                float sum = 0.0f;
#pragma unroll
                for (int t = 0; t < 4; ++t)
#pragma unroll
                    for (int r = 0; r < 4; ++r) {
                        sc[s][t][r] = exp2_fast(sc[s][t][r]);
                        sum += sc[s][t][r];
                    }
                l_r[s] += sum;

                // ---- pack P: k-slot quad*8+j -> kv = 16*t(j)+4*quad+(j&3) ----
                union { bf16x8 v8; unsigned int w[4]; } pf01, pf23;
                pf01.w[0] = cvt_pk_bf16(sc[s][0][0], sc[s][0][1]);
                pf01.w[1] = cvt_pk_bf16(sc[s][0][2], sc[s][0][3]);
                pf01.w[2] = cvt_pk_bf16(sc[s][1][0], sc[s][1][1]);
                pf01.w[3] = cvt_pk_bf16(sc[s][1][2], sc[s][1][3]);
                pf23.w[0] = cvt_pk_bf16(sc[s][2][0], sc[s][2][1]);
                pf23.w[1] = cvt_pk_bf16(sc[s][2][2], sc[s][2][3]);
                pf23.w[2] = cvt_pk_bf16(sc[s][3][0], sc[s][3][1]);
                pf23.w[3] = cvt_pk_bf16(sc[s][3][2], sc[s][3][3]);

                // ---- PV: V kv-permuted -> both B-frags are b128 reads ----
                __builtin_amdgcn_s_setprio(1);
#pragma unroll
                for (int dt = 0; dt < 4; ++dt) {
                    const short* vb = &Vsc[(dt * 16 + l16) * KSTR + quad * 16];
                    bf16x8 vf01 = *(const bf16x8*)(vb);
                    bf16x8 vf23 = *(const bf16x8*)(vb + 8);
                    oacc[s][dt] = __builtin_amdgcn_mfma_f32_16x16x32_bf16(pf01.v8, vf01, oacc[s][dt], 0, 0, 0);
                    oacc[s][dt] = __builtin_amdgcn_mfma_f32_16x16x32_bf16(pf23.v8, vf23, oacc[s][dt], 0, 0, 0);
                }
                __builtin_amdgcn_s_setprio(0);
            }
        }

        // write chunk c+1 into the other buffer
        if (c + 1 < nch) {
            short* d = cur ? lds0 : lds1;
            *(uint4*)d = r0; *(uint4*)(d + 8) = r1;
        }
    }

#pragma unroll
    for (int s = 0; s < 2; ++s) {
        float tot = l_r[s];
        tot += __shfl_xor(tot, 16);
        tot += __shfl_xor(tot, 32);
        const float linv = 1.0f / tot;  // at q = qw + l16
#pragma unroll
        for (int r = 0; r < 4; ++r) {
            const float inv = __shfl(linv, quad * 4 + r, 16);
            const int qabs = w32 + s * 16 + quad * 4 + r;
            unsigned short* op = Oatt + (long)(b * S_LEN + qabs) * DIMSZ + h * HD;
#pragma unroll
            for (int dt = 0; dt < 4; ++dt)
                op[dt * 16 + l16] = f2bf(oacc[s][dt][r] * inv);
        }
    }
}

// ---------------------------------------------------------------------------
extern "C" void kernel_launch(void* const* d_in, const int* in_sizes, int n_in,
                              void* d_out, int out_size, void* d_ws, size_t ws_size,
                              hipStream_t stream)
{
    const float* x    = (const float*)d_in[0];
    const float* wqkv = (const float*)d_in[1];
    const float* wo   = (const float*)d_in[2];
    const float* qg   = (const float*)d_in[3];
    const float* qb   = (const float*)d_in[4];
    const float* kg   = (const float*)d_in[5];
    const float* kb   = (const float*)d_in[6];
    const float* fc   = (const float*)d_in[7];
    const float* fs   = (const float*)d_in[8];
    // d_in[9] = mask: tril(NEG) — applied analytically

    char* ws = (char*)d_ws;
    // fast layout (bytes):
    // [0,        16777216)  Q bf16
    // [16777216, 20971520)  K bf16
    // [20971520, 25165824)  V bf16
    // [25165824, 41943040)  Oatt bf16         (x16 overlay during phase 1)
    // [41943040, 46137344)  Vt bf16           (w16 overlay during phase 1)
    // [46137344, 54525952)  Wot bf16          (w16 tail; free after QKV GEMM)
    unsigned short* Qr   = (unsigned short*)ws;
    unsigned short* Kr   = (unsigned short*)(ws + 16777216);
    unsigned short* Vr   = (unsigned short*)(ws + 20971520);
    unsigned short* Oatt = (unsigned short*)(ws + 25165824);
    unsigned short* x16  = (unsigned short*)(ws + 25165824);
    unsigned short* w16  = (unsigned short*)(ws + 41943040);
    unsigned short* Vt   = (unsigned short*)(ws + 41943040);
    unsigned short* WotF = (unsigned short*)(ws + 46137344);  // fast path
    unsigned short* Wot0 = (unsigned short*)ws;               // fallback (dead Q)

    dim3 blk(256);
    const bool fast = ws_size >= 54525952ull;

    if (fast) {
        convert_bf16_2<<<dim3(4096 + 3072), blk, 0, stream>>>(x, x16, wqkv, w16, 4096);
        // QKV GEMM: 256x256 tile, 8 waves, overlapped staging (one barrier/K-tile)
        gemm_qkv_256<<<dim3(QKV_N / 256, NTOK / 256), dim3(512), 0, stream>>>(
            x16, w16, Qr, Kr, Vr, NTOK, QKV_N, DIMSZ);
        // V->Vt + LN/RoPE + wo^T in ONE launch (block-range dispatch)
        prep_kernel<<<dim3(512 + 10240 + 4096), blk, 0, stream>>>(
            Vr, Vt, Qr, Kr, qg, qb, kg, kb, fc, fs, wo, WotF);
        attn_mfma<<<dim3(NBATCH * NH, S_LEN / 256), dim3(512), 0, stream>>>(
            Qr, Kr, Vt, Oatt);
        gemm_bt128<0, 64><<<dim3(DIMSZ / 128, NTOK / 64), blk, 0, stream>>>(
            Oatt, WotF, (float*)d_out, nullptr, nullptr, nullptr, NTOK, DIMSZ, DIMSZ);
    } else {
        gemm_qkv_mfma<<<dim3(QKV_N / 64, NTOK / 64), blk, 0, stream>>>(
            x, wqkv, Qr, Kr, Vr, NTOK, QKV_N, DIMSZ);
        transpose_v<<<dim3(S_LEN / 64, NBATCH * NKV), blk, 0, stream>>>(Vr, Vt);
        lnrope_kernel<<<dim3(NTOK * 40 / 16), blk, 0, stream>>>(
            Qr, Kr, qg, qb, kg, kb, fc, fs);
        attn_mfma<<<dim3(NBATCH * NH, S_LEN / 256), dim3(512), 0, stream>>>(
            Qr, Kr, Vt, Oatt);
        transpose_wo<<<dim3(64, 64), blk, 0, stream>>>(wo, Wot0, DIMSZ);
        gemm_bt128<0, 64><<<dim3(DIMSZ / 128, NTOK / 64), blk, 0, stream>>>(
            Oatt, Wot0, (float*)d_out, nullptr, nullptr, nullptr, NTOK, DIMSZ, DIMSZ);
    }
}

// Round 14
// 314.952 us; speedup vs baseline: 1.0162x; 1.0162x over previous
//
#include <hip/hip_runtime.h>

#define S_LEN 2048
#define NBATCH 2
#define DIMSZ 2048
#define NH 32
#define NKV 8
#define HD 64
#define QKV_N 3072
#define NTOK 4096  // NBATCH * S_LEN

typedef __attribute__((ext_vector_type(8))) short bf16x8;
typedef __attribute__((ext_vector_type(4))) short bf16x4;
typedef __attribute__((ext_vector_type(4))) float f32x4;

#define QSCALE 0.18033688011112042f  // (1/sqrt(64)) * log2(e)

__device__ __forceinline__ float bf2f(unsigned short u) {
    union { unsigned int i; float f; } v; v.i = ((unsigned int)u) << 16; return v.f;
}
__device__ __forceinline__ unsigned short f2bf(float f) {
    union { float f; unsigned int i; } v; v.f = f;
    unsigned int r = v.i + 0x7FFFu + ((v.i >> 16) & 1u);  // RNE
    return (unsigned short)(r >> 16);
}
// single-instruction 2^x (v_exp_f32 computes exp2)
__device__ __forceinline__ float exp2_fast(float x) {
    float r; asm("v_exp_f32 %0, %1" : "=v"(r) : "v"(x)); return r;
}
// pack two f32 -> one dword of 2x bf16 (lo=a, hi=b), hardware RNE
__device__ __forceinline__ unsigned int cvt_pk_bf16(float a, float b) {
    unsigned int r;
    asm("v_cvt_pk_bf16_f32 %0, %1, %2" : "=v"(r) : "v"(a), "v"(b));
    return r;
}

// async global->LDS, 16 B per lane; lds ptr must be wave-uniform base
__device__ __forceinline__ void gld_lds16(const unsigned short* g, short* l) {
    __builtin_amdgcn_global_load_lds(
        (const __attribute__((address_space(1))) unsigned int*)g,
        (__attribute__((address_space(3))) unsigned int*)l, 16, 0, 0);
}

// ---------------------------------------------------------------------------
// fp32 -> bf16 elementwise convert, 8 elems/thread; TWO arrays in one launch
// ---------------------------------------------------------------------------
__global__ __launch_bounds__(256) void convert_bf16_2(
    const float* __restrict__ a, unsigned short* __restrict__ da,
    const float* __restrict__ b, unsigned short* __restrict__ db, int ablk)
{
    const float* src;
    unsigned short* dst;
    long base;
    if ((int)blockIdx.x < ablk) { src = a; dst = da; base = (long)blockIdx.x; }
    else                        { src = b; dst = db; base = (long)blockIdx.x - ablk; }
    const long i = (base * 256 + threadIdx.x) * 8;
    float4 x = *(const float4*)(src + i);
    float4 y = *(const float4*)(src + i + 4);
    union { uint4 u; unsigned short s[8]; } o;
    o.s[0] = f2bf(x.x); o.s[1] = f2bf(x.y); o.s[2] = f2bf(x.z); o.s[3] = f2bf(x.w);
    o.s[4] = f2bf(y.x); o.s[5] = f2bf(y.y); o.s[6] = f2bf(y.z); o.s[7] = f2bf(y.w);
    *(uint4*)(dst + i) = o.u;
}

// ---------------------------------------------------------------------------
// BMx128 GEMM, BK=64, bank-conflict-free (verified SQ_LDS_BANK_CONFLICT=0).
// EPI 0: fp32 C.  EPI 1: bf16 scatter to split Q/K/V.
// XCD-aware block swizzle (T1): grids are %8==0, simple bijective remap.
// ---------------------------------------------------------------------------
template <int EPI, int BM>
__global__ __launch_bounds__(256) void gemm_bt128(
    const unsigned short* __restrict__ A, const unsigned short* __restrict__ Bt,
    float* __restrict__ C,
    unsigned short* __restrict__ Qb, unsigned short* __restrict__ Kb,
    unsigned short* __restrict__ Vb, int M, int N, int K)
{
    constexpr int TM = BM / 32;                   // row-tiles per wave
    __shared__ __align__(16) short As[BM * 64];   // [row][k], swizzled granules
    __shared__ __align__(16) short Bs[128 * 64];

    const int tid = threadIdx.x;
    const int lane = tid & 63;
    const int wid = tid >> 6;
    const int quad = lane >> 4;
    const int l16 = lane & 15;

    // XCD swizzle: each XCD gets a contiguous chunk of the linear grid
    const int nwg = gridDim.x * gridDim.y;
    const int lin = blockIdx.y * gridDim.x + blockIdx.x;
    const int cpx = nwg >> 3;                      // nwg % 8 == 0 for our grids
    const int swz = (lin & 7) * cpx + (lin >> 3);
    const int bx = swz % gridDim.x;
    const int by = swz / gridDim.x;

    const int m0 = by * BM;
    const int n0 = bx * 128;
    const int wm = (wid & 1) * (BM / 2);
    const int wn = (wid >> 1) * 64;

    f32x4 acc[TM][4] = {};

    // staging: 8 lanes per row, 16B granule each; source granule pre-swizzled
    const int srow8 = lane >> 3;                  // 0..7 (row within 8-row blk)
    const int scol8 = ((lane & 7) ^ srow8) * 8;   // swizzled granule (shorts)
    const unsigned short* Ag = A + (long)(m0 + srow8) * K + scol8;
    const unsigned short* Bg = Bt + (long)(n0 + srow8) * K + scol8;
    const int gsw = l16 & 7;                      // read-side XOR key

    for (int k0 = 0; k0 < K; k0 += 64) {
        __syncthreads();
#pragma unroll
        for (int bc = 0; bc < 4; ++bc) {
            const int blk = wid + bc * 4;         // 0..15 (8-row blocks)
            if (bc < BM / 32)
                gld_lds16(Ag + (long)(blk * 8) * K + k0, &As[blk * 512]);
            gld_lds16(Bg + (long)(blk * 8) * K + k0, &Bs[blk * 512]);
        }
        __syncthreads();

#pragma unroll
        for (int ko = 0; ko < 2; ++ko) {
            const int ga = ((quad + ko * 4) ^ gsw) * 8;  // swizzled frag granule
            bf16x8 af[TM], bf[4];
#pragma unroll
            for (int t = 0; t < TM; ++t)
                af[t] = *(const bf16x8*)&As[(wm + t * 16 + l16) * 64 + ga];
#pragma unroll
            for (int t = 0; t < 4; ++t)
                bf[t] = *(const bf16x8*)&Bs[(wn + t * 16 + l16) * 64 + ga];
#pragma unroll
            for (int tm = 0; tm < TM; ++tm)
#pragma unroll
                for (int tn = 0; tn < 4; ++tn)
                    acc[tm][tn] = __builtin_amdgcn_mfma_f32_16x16x32_bf16(af[tm], bf[tn], acc[tm][tn], 0, 0, 0);
        }
    }

    if (EPI == 0) {
#pragma unroll
        for (int tm = 0; tm < TM; ++tm)
#pragma unroll
            for (int i = 0; i < 4; ++i) {
                const int row = m0 + wm + tm * 16 + quad * 4 + i;
#pragma unroll
                for (int tn = 0; tn < 4; ++tn)
                    C[(long)row * N + n0 + wn + tn * 16 + l16] = acc[tm][tn][i];
            }
    } else {
        const int slot = (n0 + wn) >> 6;  // wave-uniform: 0..47
#pragma unroll
        for (int tm = 0; tm < TM; ++tm)
#pragma unroll
            for (int i = 0; i < 4; ++i) {
                const int row = m0 + wm + tm * 16 + quad * 4 + i;
                const int b = row >> 11, s = row & 2047;
                unsigned short* base;
                if (slot < 32)      base = Qb + ((long)(b * NH + slot) * S_LEN + s) * HD;
                else if (slot < 40) base = Kb + ((long)(b * NKV + (slot - 32)) * S_LEN + s) * HD;
                else                base = Vb + ((long)(b * NKV + (slot - 40)) * S_LEN + s) * HD;
#pragma unroll
                for (int tn = 0; tn < 4; ++tn)
                    base[tn * 16 + l16] = f2bf(acc[tm][tn][i]);
            }
    }
}

// ---------------------------------------------------------------------------
// PREP kernel (fast path): three independent small jobs in ONE launch:
//   [0, 512)        V -> Vt (kv-permuted transpose)
//   [512, 10752)    LN+RoPE in-place on Q and K
//   [10752, 14848)  wo^T -> bf16 (Wot)
// ---------------------------------------------------------------------------
__global__ __launch_bounds__(256) void prep_kernel(
    const unsigned short* __restrict__ V, unsigned short* __restrict__ Vt,
    unsigned short* __restrict__ Qb, unsigned short* __restrict__ Kb,
    const float* __restrict__ qg, const float* __restrict__ qb,
    const float* __restrict__ kg, const float* __restrict__ kb,
    const float* __restrict__ fcos, const float* __restrict__ fsin,
    const float* __restrict__ wo, unsigned short* __restrict__ Wot)
{
    __shared__ __align__(16) unsigned short shbuf[64 * 72];
    const int bid = blockIdx.x;
    const int tid = threadIdx.x;

    if (bid < 512) {
        unsigned short (*tile)[72] = (unsigned short(*)[72])shbuf;
        const int bk = bid >> 5;
        const int s0 = (bid & 31) * 64;
        const int r = tid >> 2, c0 = (tid & 3) * 16;

        const unsigned short* src = V + ((long)bk * S_LEN + s0 + r) * HD + c0;
        *(uint4*)&tile[r][c0]     = *(const uint4*)src;
        *(uint4*)&tile[r][c0 + 8] = *(const uint4*)(src + 8);
        __syncthreads();

        union { uint4 u[2]; unsigned short s[16]; } o;
        const int q = tid & 3;
#pragma unroll
        for (int j = 0; j < 16; ++j) {
            const int t = 2 * (j >> 3) + ((j >> 2) & 1);
            const int kv = t * 16 + q * 4 + (j & 3);
            o.s[j] = tile[kv][r];
        }
        unsigned short* dst = Vt + ((long)bk * HD + r) * S_LEN + s0 + c0;
        *(uint4*)dst       = o.u[0];
        *(uint4*)(dst + 8) = o.u[1];
    } else if (bid < 10752) {
        const int l16 = tid & 15;
        const int rgrp = tid >> 4;
        const int row = (bid - 512) * 16 + rgrp;
        const int token = row / 40;
        const int slot = row - token * 40;
        const int b = token >> 11;
        const int s = token & 2047;
        const bool isq = slot < 32;

        unsigned short* base = isq
            ? Qb + ((long)(b * NH + slot) * S_LEN + s) * HD
            : Kb + ((long)(b * NKV + (slot - 32)) * S_LEN + s) * HD;

        union { ushort4 u; unsigned short h[4]; } in;
        in.u = *(const ushort4*)(base + l16 * 4);
        float f0 = bf2f(in.h[0]), f1 = bf2f(in.h[1]);
        float f2 = bf2f(in.h[2]), f3 = bf2f(in.h[3]);

        float sum = (f0 + f1) + (f2 + f3);
#pragma unroll
        for (int off = 1; off < 16; off <<= 1) sum += __shfl_xor(sum, off);
        const float mu = sum * (1.0f / 64.0f);
        const float d0v = f0 - mu, d1v = f1 - mu, d2v = f2 - mu, d3v = f3 - mu;
        float vs = (d0v * d0v + d1v * d1v) + (d2v * d2v + d3v * d3v);
#pragma unroll
        for (int off = 1; off < 16; off <<= 1) vs += __shfl_xor(vs, off);
        const float rs = rsqrtf(vs * (1.0f / 64.0f) + 1e-5f);

        const float4 g  = *(const float4*)((isq ? qg : kg) + l16 * 4);
        const float4 be = *(const float4*)((isq ? qb : kb) + l16 * 4);
        float n0 = d0v * rs * g.x + be.x;
        float n1 = d1v * rs * g.y + be.y;
        float n2 = d2v * rs * g.z + be.z;
        float n3 = d3v * rs * g.w + be.w;

        const float2 cs = *(const float2*)(fcos + s * 32 + l16 * 2);
        const float2 sn = *(const float2*)(fsin + s * 32 + l16 * 2);
        float o0 = n0 * cs.x - n1 * sn.x;
        float o1 = n0 * sn.x + n1 * cs.x;
        float o2 = n2 * cs.y - n3 * sn.y;
        float o3 = n2 * sn.y + n3 * cs.y;

        if (isq) { o0 *= QSCALE; o1 *= QSCALE; o2 *= QSCALE; o3 *= QSCALE; }

        union { ushort4 u; unsigned short h[4]; } out;
        out.h[0] = f2bf(o0); out.h[1] = f2bf(o1);
        out.h[2] = f2bf(o2); out.h[3] = f2bf(o3);
        *(ushort4*)(base + l16 * 4) = out.u;
    } else {
        unsigned short (*tile)[33] = (unsigned short(*)[33])shbuf;
        const int b2 = bid - 10752;
        const int bx = b2 & 63, by = b2 >> 6;
        const int tx = tid & 31;
        const int ty = tid >> 5;
        const int x = bx * 32 + tx;
        const int y0 = by * 32;
        for (int j = ty; j < 32; j += 8)
            tile[j][tx] = f2bf(wo[(long)(y0 + j) * DIMSZ + x]);
        __syncthreads();
        const int x2 = by * 32 + tx;
        const int y2 = bx * 32;
        for (int j = ty; j < 32; j += 8)
            Wot[(long)(y2 + j) * DIMSZ + x2] = tile[tx][j];
    }
}

// ---------------------------------------------------------------------------
// Fallback QKV GEMM (fp32 in, register-convert staging, 64x64).
// ---------------------------------------------------------------------------
__global__ __launch_bounds__(256) void gemm_qkv_mfma(
    const float* __restrict__ A, const float* __restrict__ Bt,
    unsigned short* __restrict__ Qb, unsigned short* __restrict__ Kb,
    unsigned short* __restrict__ Vb, int M, int N, int K)
{
    const int LW = 40;
    __shared__ __align__(16) short As[64 * LW];
    __shared__ __align__(16) short Bs[64 * LW];

    const int tid = threadIdx.x;
    const int lane = tid & 63;
    const int wid = tid >> 6;
    const int quad = lane >> 4;
    const int l16 = lane & 15;

    const int m0 = blockIdx.y * 64;
    const int n0 = blockIdx.x * 64;
    const int wm = (wid >> 1) * 32;
    const int wn = (wid & 1) * 32;

    f32x4 acc[2][2] = {};

    const int srow = tid >> 2;
    const int scol = (tid & 3) * 8;

    const float* Ag = A + (long)(m0 + srow) * K + scol;
    const float* Bg = Bt + (long)(n0 + srow) * K + scol;
    short* da = &As[srow * LW + scol];
    short* db = &Bs[srow * LW + scol];

    for (int k0 = 0; k0 < K; k0 += 32) {
        __syncthreads();
        float4 a0 = *(const float4*)(Ag + k0), a1 = *(const float4*)(Ag + k0 + 4);
        float4 b0 = *(const float4*)(Bg + k0), b1 = *(const float4*)(Bg + k0 + 4);
        union { uint4 u; short s[8]; } pa, pb;
        pa.s[0] = (short)f2bf(a0.x); pa.s[1] = (short)f2bf(a0.y);
        pa.s[2] = (short)f2bf(a0.z); pa.s[3] = (short)f2bf(a0.w);
        pa.s[4] = (short)f2bf(a1.x); pa.s[5] = (short)f2bf(a1.y);
        pa.s[6] = (short)f2bf(a1.z); pa.s[7] = (short)f2bf(a1.w);
        pb.s[0] = (short)f2bf(b0.x); pb.s[1] = (short)f2bf(b0.y);
        pb.s[2] = (short)f2bf(b0.z); pb.s[3] = (short)f2bf(b0.w);
        pb.s[4] = (short)f2bf(b1.x); pb.s[5] = (short)f2bf(b1.y);
        pb.s[6] = (short)f2bf(b1.z); pb.s[7] = (short)f2bf(b1.w);
        *(uint4*)da = pa.u;
        *(uint4*)db = pb.u;
        __syncthreads();

        bf16x8 bfr[2];
#pragma unroll
        for (int tc = 0; tc < 2; ++tc)
            bfr[tc] = *(const bf16x8*)&Bs[(wn + tc * 16 + l16) * LW + quad * 8];
#pragma unroll
        for (int tr = 0; tr < 2; ++tr) {
            bf16x8 a = *(const bf16x8*)&As[(wm + tr * 16 + l16) * LW + quad * 8];
#pragma unroll
            for (int tc = 0; tc < 2; ++tc)
                acc[tr][tc] = __builtin_amdgcn_mfma_f32_16x16x32_bf16(a, bfr[tc], acc[tr][tc], 0, 0, 0);
        }
    }

    const int slot = n0 >> 6;
#pragma unroll
    for (int tr = 0; tr < 2; ++tr)
#pragma unroll
        for (int tc = 0; tc < 2; ++tc)
#pragma unroll
            for (int i = 0; i < 4; ++i) {
                const int row = m0 + wm + tr * 16 + quad * 4 + i;
                const int d = wn + tc * 16 + l16;
                const int b = row >> 11, s = row & 2047;
                unsigned short v = f2bf(acc[tr][tc][i]);
                if (slot < 32)
                    Qb[((long)(b * NH + slot) * S_LEN + s) * HD + d] = v;
                else if (slot < 40)
                    Kb[((long)(b * NKV + (slot - 32)) * S_LEN + s) * HD + d] = v;
                else
                    Vb[((long)(b * NKV + (slot - 40)) * S_LEN + s) * HD + d] = v;
            }
}

// ---------------------------------------------------------------------------
// Fallback: in-place LayerNorm(64) + RoPE on Q and K.
// ---------------------------------------------------------------------------
__global__ __launch_bounds__(256) void lnrope_kernel(
    unsigned short* __restrict__ Qb, unsigned short* __restrict__ Kb,
    const float* __restrict__ qg, const float* __restrict__ qb,
    const float* __restrict__ kg, const float* __restrict__ kb,
    const float* __restrict__ fcos, const float* __restrict__ fsin)
{
    const int tid = threadIdx.x;
    const int l16 = tid & 15;
    const int rgrp = tid >> 4;
    const int row = blockIdx.x * 16 + rgrp;
    const int token = row / 40;
    const int slot = row - token * 40;
    const int b = token >> 11;
    const int s = token & 2047;
    const bool isq = slot < 32;

    unsigned short* base = isq
        ? Qb + ((long)(b * NH + slot) * S_LEN + s) * HD
        : Kb + ((long)(b * NKV + (slot - 32)) * S_LEN + s) * HD;

    union { ushort4 u; unsigned short h[4]; } in;
    in.u = *(const ushort4*)(base + l16 * 4);
    float f0 = bf2f(in.h[0]), f1 = bf2f(in.h[1]);
    float f2 = bf2f(in.h[2]), f3 = bf2f(in.h[3]);

    float sum = (f0 + f1) + (f2 + f3);
#pragma unroll
    for (int off = 1; off < 16; off <<= 1) sum += __shfl_xor(sum, off);
    const float mu = sum * (1.0f / 64.0f);
    const float d0v = f0 - mu, d1v = f1 - mu, d2v = f2 - mu, d3v = f3 - mu;
    float vs = (d0v * d0v + d1v * d1v) + (d2v * d2v + d3v * d3v);
#pragma unroll
    for (int off = 1; off < 16; off <<= 1) vs += __shfl_xor(vs, off);
    const float rs = rsqrtf(vs * (1.0f / 64.0f) + 1e-5f);

    const float4 g  = *(const float4*)((isq ? qg : kg) + l16 * 4);
    const float4 be = *(const float4*)((isq ? qb : kb) + l16 * 4);
    float n0 = d0v * rs * g.x + be.x;
    float n1 = d1v * rs * g.y + be.y;
    float n2 = d2v * rs * g.z + be.z;
    float n3 = d3v * rs * g.w + be.w;

    const float2 cs = *(const float2*)(fcos + s * 32 + l16 * 2);
    const float2 sn = *(const float2*)(fsin + s * 32 + l16 * 2);
    float o0 = n0 * cs.x - n1 * sn.x;
    float o1 = n0 * sn.x + n1 * cs.x;
    float o2 = n2 * cs.y - n3 * sn.y;
    float o3 = n2 * sn.y + n3 * cs.y;

    if (isq) { o0 *= QSCALE; o1 *= QSCALE; o2 *= QSCALE; o3 *= QSCALE; }

    union { ushort4 u; unsigned short h[4]; } out;
    out.h[0] = f2bf(o0); out.h[1] = f2bf(o1);
    out.h[2] = f2bf(o2); out.h[3] = f2bf(o3);
    *(ushort4*)(base + l16 * 4) = out.u;
}

// ---------------------------------------------------------------------------
// Fallback: V -> V^T in global, kv-PERMUTED within each 64-chunk.
// ---------------------------------------------------------------------------
__global__ __launch_bounds__(256) void transpose_v(
    const unsigned short* __restrict__ V, unsigned short* __restrict__ Vt)
{
    __shared__ unsigned short tile[64][72];
    const int tid = threadIdx.x;
    const int bk = blockIdx.y;
    const int s0 = blockIdx.x * 64;
    const int r = tid >> 2, c0 = (tid & 3) * 16;

    const unsigned short* src = V + ((long)bk * S_LEN + s0 + r) * HD + c0;
    *(uint4*)&tile[r][c0]     = *(const uint4*)src;
    *(uint4*)&tile[r][c0 + 8] = *(const uint4*)(src + 8);
    __syncthreads();

    union { uint4 u[2]; unsigned short s[16]; } o;
    const int q = tid & 3;
#pragma unroll
    for (int j = 0; j < 16; ++j) {
        const int t = 2 * (j >> 3) + ((j >> 2) & 1);
        const int kv = t * 16 + q * 4 + (j & 3);
        o.s[j] = tile[kv][r];
    }
    unsigned short* dst = Vt + ((long)bk * HD + r) * S_LEN + s0 + c0;
    *(uint4*)dst       = o.u[0];
    *(uint4*)(dst + 8) = o.u[1];
}

// ---------------------------------------------------------------------------
// Fallback: wo^T -> bf16, 2048x2048
// ---------------------------------------------------------------------------
__global__ __launch_bounds__(256) void transpose_wo(
    const float* __restrict__ in, unsigned short* __restrict__ out, int n)
{
    __shared__ unsigned short tile[32][33];
    const int tx = threadIdx.x & 31;
    const int ty = threadIdx.x >> 5;
    const int x = blockIdx.x * 32 + tx;
    const int y0 = blockIdx.y * 32;
    for (int j = ty; j < 32; j += 8) tile[j][tx] = f2bf(in[(long)(y0 + j) * n + x]);
    __syncthreads();
    const int x2 = blockIdx.y * 32 + tx;
    const int y2 = blockIdx.x * 32;
    for (int j = ty; j < 32; j += 8) out[(long)(y2 + j) * n + x2] = tile[tx][j];
}

// ---------------------------------------------------------------------------
// MFMA flash attention, causal (round-11 verified; unchanged).
// ---------------------------------------------------------------------------
#define KSTR 72  // LDS stride (shorts)

__global__ __launch_bounds__(512, 4) void attn_mfma(
    const unsigned short* __restrict__ Q,
    const unsigned short* __restrict__ Kin,
    const unsigned short* __restrict__ Vtg,
    unsigned short* __restrict__ Oatt)
{
    __shared__ __align__(16) short Ks[2][64 * KSTR];   // [buf][kv][hd]
    __shared__ __align__(16) short Vs[2][64 * KSTR];   // [buf][d][kv-perm]

    const int tid = threadIdx.x;
    const int lane = tid & 63;
    const int wid = tid >> 6;          // 0..7
    const int quad = lane >> 4;
    const int l16 = lane & 15;

    const int bh = blockIdx.x;
    const int b = bh >> 5, h = bh & 31, kvh = h >> 2;
    const int NY = S_LEN / 128;                 // 16 q-tiles
    const int tlo = blockIdx.y;                 // 0..7
    const int thi = (NY - 1) - tlo;             // 15..8
    const int tq = (wid >> 2) ? thi : tlo;      // this wave's q-tile
    const int w32 = tq * 128 + (wid & 3) * 32;  // this wave's 32 q-rows

    const unsigned short* Qb = Q + (long)(b * NH + h) * S_LEN * HD;
    const unsigned short* Kb = Kin + (long)(b * NKV + kvh) * S_LEN * HD;
    const unsigned short* Vtb = Vtg + (long)(b * NKV + kvh) * HD * S_LEN;

    bf16x8 qf[2][2];  // [sub][half]
#pragma unroll
    for (int s = 0; s < 2; ++s) {
        qf[s][0] = *(const bf16x8*)(Qb + (long)(w32 + s * 16 + l16) * HD + quad * 8);
        qf[s][1] = *(const bf16x8*)(Qb + (long)(w32 + s * 16 + l16) * HD + 32 + quad * 8);
    }

    f32x4 oacc[2][4] = {};
    float l_r[2] = {0.0f, 0.0f};   // per-lane partial denominators

    // staging: tid<256 -> K, tid>=256 -> V; 32B per thread
    const bool stK = tid < 256;
    const int st = stK ? tid : tid - 256;
    const int kk = st >> 2;           // row (K: kv row, V: d row)
    const int d0 = (st & 3) * 16;     // 16-short segment
    const unsigned short* gsrc = stK
        ? Kb + (long)kk * HD + d0
        : Vtb + (long)kk * S_LEN + d0;
    const long ginc = stK ? (long)64 * HD : 64;  // per-chunk advance (shorts)
    short* const lds0 = stK ? &Ks[0][kk * KSTR + d0] : &Vs[0][kk * KSTR + d0];
    short* const lds1 = stK ? &Ks[1][kk * KSTR + d0] : &Vs[1][kk * KSTR + d0];

    const int nch = 2 * thi + 2;      // hi tile defines the chunk range

    uint4 r0, r1;
    {   // prologue: chunk 0 -> regs -> buf0
        r0 = *(const uint4*)gsrc; r1 = *(const uint4*)(gsrc + 8);
        *(uint4*)lds0 = r0; *(uint4*)(lds0 + 8) = r1;
    }

    for (int c = 0; c < nch; ++c) {
        const int cur = c & 1;
        const int kbase = c * 64;
        __syncthreads();  // buf[cur] ready; all waves done reading buf[cur^1]

        // issue loads for chunk c+1 (latency hides under compute of chunk c)
        if (c + 1 < nch) {
            const unsigned short* p = gsrc + (long)(c + 1) * ginc;
            r0 = *(const uint4*)p; r1 = *(const uint4*)(p + 8);
        }

        if (kbase <= w32 + 31) {
            const bool act0 = (kbase <= w32 + 15);  // subtile 0 active?
            const short* Ksc = Ks[cur];
            const short* Vsc = Vs[cur];

            // ---- QK^T swapped, K-frags read once, shared by both subtiles:
            //      sc[s][t][r] = S[kv=kbase+16t+4*quad+r][q=qw+l16]
            f32x4 sc[2][4];
            __builtin_amdgcn_s_setprio(1);
#pragma unroll
            for (int t = 0; t < 4; ++t) {
                bf16x8 kf0 = *(const bf16x8*)&Ksc[(t * 16 + l16) * KSTR + quad * 8];
                bf16x8 kf1 = *(const bf16x8*)&Ksc[(t * 16 + l16) * KSTR + 32 + quad * 8];
#pragma unroll
                for (int s = 0; s < 2; ++s) {
                    if (s == 0 && !act0) continue;
                    f32x4 z = {};
                    z = __builtin_amdgcn_mfma_f32_16x16x32_bf16(kf0, qf[s][0], z, 0, 0, 0);
                    sc[s][t] = __builtin_amdgcn_mfma_f32_16x16x32_bf16(kf1, qf[s][1], z, 0, 0, 0);
                }
            }
            __builtin_amdgcn_s_setprio(0);

#pragma unroll
            for (int s = 0; s < 2; ++s) {
                if (s == 0 && !act0) continue;
                const int qw = w32 + s * 16;
                const bool diag = (kbase + 63 > qw);  // wave-uniform

                // ---- mask in place (diag only); exp2(-1e30) == 0 ----
                if (diag) {
                    const int rel = qw + l16 - kbase;
#pragma unroll
                    for (int t = 0; t < 4; ++t)
#pragma unroll
                        for (int r = 0; r < 4; ++r) {
                            const int kvrel = t * 16 + quad * 4 + r;
                            if (kvrel > rel) sc[s][t][r] = -1e30f;
                        }
                }

                // ---- raw exp2 (shift-invariant softmax), per-lane partial sum
                float sum = 0.0f;
#pragma unroll
                for (int t = 0; t < 4; ++t)
#pragma unroll
                    for (int r = 0; r < 4; ++r) {
                        sc[s][t][r] = exp2_fast(sc[s][t][r]);
                        sum += sc[s][t][r];
                    }
                l_r[s] += sum;

                // ---- pack P: k-slot quad*8+j -> kv = 16*t(j)+4*quad+(j&3) ----
                union { bf16x8 v8; unsigned int w[4]; } pf01, pf23;
                pf01.w[0] = cvt_pk_bf16(sc[s][0][0], sc[s][0][1]);
                pf01.w[1] = cvt_pk_bf16(sc[s][0][2], sc[s][0][3]);
                pf01.w[2] = cvt_pk_bf16(sc[s][1][0], sc[s][1][1]);
                pf01.w[3] = cvt_pk_bf16(sc[s][1][2], sc[s][1][3]);
                pf23.w[0] = cvt_pk_bf16(sc[s][2][0], sc[s][2][1]);
                pf23.w[1] = cvt_pk_bf16(sc[s][2][2], sc[s][2][3]);
                pf23.w[2] = cvt_pk_bf16(sc[s][3][0], sc[s][3][1]);
                pf23.w[3] = cvt_pk_bf16(sc[s][3][2], sc[s][3][3]);

                // ---- PV: V kv-permuted -> both B-frags are b128 reads ----
                __builtin_amdgcn_s_setprio(1);
#pragma unroll
                for (int dt = 0; dt < 4; ++dt) {
                    const short* vb = &Vsc[(dt * 16 + l16) * KSTR + quad * 16];
                    bf16x8 vf01 = *(const bf16x8*)(vb);
                    bf16x8 vf23 = *(const bf16x8*)(vb + 8);
                    oacc[s][dt] = __builtin_amdgcn_mfma_f32_16x16x32_bf16(pf01.v8, vf01, oacc[s][dt], 0, 0, 0);
                    oacc[s][dt] = __builtin_amdgcn_mfma_f32_16x16x32_bf16(pf23.v8, vf23, oacc[s][dt], 0, 0, 0);
                }
                __builtin_amdgcn_s_setprio(0);
            }
        }

        // write chunk c+1 into the other buffer
        if (c + 1 < nch) {
            short* d = cur ? lds0 : lds1;
            *(uint4*)d = r0; *(uint4*)(d + 8) = r1;
        }
    }

#pragma unroll
    for (int s = 0; s < 2; ++s) {
        float tot = l_r[s];
        tot += __shfl_xor(tot, 16);
        tot += __shfl_xor(tot, 32);
        const float linv = 1.0f / tot;  // at q = qw + l16
#pragma unroll
        for (int r = 0; r < 4; ++r) {
            const float inv = __shfl(linv, quad * 4 + r, 16);
            const int qabs = w32 + s * 16 + quad * 4 + r;
            unsigned short* op = Oatt + (long)(b * S_LEN + qabs) * DIMSZ + h * HD;
#pragma unroll
            for (int dt = 0; dt < 4; ++dt)
                op[dt * 16 + l16] = f2bf(oacc[s][dt][r] * inv);
        }
    }
}

// ---------------------------------------------------------------------------
extern "C" void kernel_launch(void* const* d_in, const int* in_sizes, int n_in,
                              void* d_out, int out_size, void* d_ws, size_t ws_size,
                              hipStream_t stream)
{
    const float* x    = (const float*)d_in[0];
    const float* wqkv = (const float*)d_in[1];
    const float* wo   = (const float*)d_in[2];
    const float* qg   = (const float*)d_in[3];
    const float* qb   = (const float*)d_in[4];
    const float* kg   = (const float*)d_in[5];
    const float* kb   = (const float*)d_in[6];
    const float* fc   = (const float*)d_in[7];
    const float* fs   = (const float*)d_in[8];
    // d_in[9] = mask: tril(NEG) — applied analytically

    char* ws = (char*)d_ws;
    // fast layout (bytes):
    // [0,        16777216)  Q bf16
    // [16777216, 20971520)  K bf16
    // [20971520, 25165824)  V bf16
    // [25165824, 41943040)  Oatt bf16         (x16 overlay during phase 1)
    // [41943040, 46137344)  Vt bf16           (w16 overlay during phase 1)
    // [46137344, 54525952)  Wot bf16          (w16 tail; free after QKV GEMM)
    unsigned short* Qr   = (unsigned short*)ws;
    unsigned short* Kr   = (unsigned short*)(ws + 16777216);
    unsigned short* Vr   = (unsigned short*)(ws + 20971520);
    unsigned short* Oatt = (unsigned short*)(ws + 25165824);
    unsigned short* x16  = (unsigned short*)(ws + 25165824);
    unsigned short* w16  = (unsigned short*)(ws + 41943040);
    unsigned short* Vt   = (unsigned short*)(ws + 41943040);
    unsigned short* WotF = (unsigned short*)(ws + 46137344);  // fast path
    unsigned short* Wot0 = (unsigned short*)ws;               // fallback (dead Q)

    dim3 blk(256);
    const bool fast = ws_size >= 54525952ull;

    if (fast) {
        convert_bf16_2<<<dim3(4096 + 3072), blk, 0, stream>>>(x, x16, wqkv, w16, 4096);
        gemm_bt128<1, 128><<<dim3(QKV_N / 128, NTOK / 128), blk, 0, stream>>>(
            x16, w16, nullptr, Qr, Kr, Vr, NTOK, QKV_N, DIMSZ);
        // V->Vt + LN/RoPE + wo^T in ONE launch (block-range dispatch)
        prep_kernel<<<dim3(512 + 10240 + 4096), blk, 0, stream>>>(
            Vr, Vt, Qr, Kr, qg, qb, kg, kb, fc, fs, wo, WotF);
        attn_mfma<<<dim3(NBATCH * NH, S_LEN / 256), dim3(512), 0, stream>>>(
            Qr, Kr, Vt, Oatt);
        gemm_bt128<0, 64><<<dim3(DIMSZ / 128, NTOK / 64), blk, 0, stream>>>(
            Oatt, WotF, (float*)d_out, nullptr, nullptr, nullptr, NTOK, DIMSZ, DIMSZ);
    } else {
        gemm_qkv_mfma<<<dim3(QKV_N / 64, NTOK / 64), blk, 0, stream>>>(
            x, wqkv, Qr, Kr, Vr, NTOK, QKV_N, DIMSZ);
        transpose_v<<<dim3(S_LEN / 64, NBATCH * NKV), blk, 0, stream>>>(Vr, Vt);
        lnrope_kernel<<<dim3(NTOK * 40 / 16), blk, 0, stream>>>(
            Qr, Kr, qg, qb, kg, kb, fc, fs);
        attn_mfma<<<dim3(NBATCH * NH, S_LEN / 256), dim3(512), 0, stream>>>(
            Qr, Kr, Vt, Oatt);
        transpose_wo<<<dim3(64, 64), blk, 0, stream>>>(wo, Wot0, DIMSZ);
        gemm_bt128<0, 64><<<dim3(DIMSZ / 128, NTOK / 64), blk, 0, stream>>>(
            Oatt, Wot0, (float*)d_out, nullptr, nullptr, nullptr, NTOK, DIMSZ, DIMSZ);
    }
}

// Round 15
// 302.707 us; speedup vs baseline: 1.0573x; 1.0404x over previous
//
#include <hip/hip_runtime.h>

#define S_LEN 2048
#define NBATCH 2
#define DIMSZ 2048
#define NH 32
#define NKV 8
#define HD 64
#define QKV_N 3072
#define NTOK 4096  // NBATCH * S_LEN

typedef __attribute__((ext_vector_type(8))) short bf16x8;
typedef __attribute__((ext_vector_type(4))) short bf16x4;
typedef __attribute__((ext_vector_type(4))) float f32x4;

#define QSCALE 0.18033688011112042f  // (1/sqrt(64)) * log2(e)

__device__ __forceinline__ float bf2f(unsigned short u) {
    union { unsigned int i; float f; } v; v.i = ((unsigned int)u) << 16; return v.f;
}
__device__ __forceinline__ unsigned short f2bf(float f) {
    union { float f; unsigned int i; } v; v.f = f;
    unsigned int r = v.i + 0x7FFFu + ((v.i >> 16) & 1u);  // RNE
    return (unsigned short)(r >> 16);
}
// single-instruction 2^x (v_exp_f32 computes exp2)
__device__ __forceinline__ float exp2_fast(float x) {
    float r; asm("v_exp_f32 %0, %1" : "=v"(r) : "v"(x)); return r;
}
// pack two f32 -> one dword of 2x bf16 (lo=a, hi=b), hardware RNE
__device__ __forceinline__ unsigned int cvt_pk_bf16(float a, float b) {
    unsigned int r;
    asm("v_cvt_pk_bf16_f32 %0, %1, %2" : "=v"(r) : "v"(a), "v"(b));
    return r;
}

// async global->LDS, 16 B per lane; lds ptr must be wave-uniform base
__device__ __forceinline__ void gld_lds16(const unsigned short* g, short* l) {
    __builtin_amdgcn_global_load_lds(
        (const __attribute__((address_space(1))) unsigned int*)g,
        (__attribute__((address_space(3))) unsigned int*)l, 16, 0, 0);
}

// ---------------------------------------------------------------------------
// fp32 -> bf16 elementwise convert, 8 elems/thread; TWO arrays in one launch
// ---------------------------------------------------------------------------
__global__ __launch_bounds__(256) void convert_bf16_2(
    const float* __restrict__ a, unsigned short* __restrict__ da,
    const float* __restrict__ b, unsigned short* __restrict__ db, int ablk)
{
    const float* src;
    unsigned short* dst;
    long base;
    if ((int)blockIdx.x < ablk) { src = a; dst = da; base = (long)blockIdx.x; }
    else                        { src = b; dst = db; base = (long)blockIdx.x - ablk; }
    const long i = (base * 256 + threadIdx.x) * 8;
    float4 x = *(const float4*)(src + i);
    float4 y = *(const float4*)(src + i + 4);
    union { uint4 u; unsigned short s[8]; } o;
    o.s[0] = f2bf(x.x); o.s[1] = f2bf(x.y); o.s[2] = f2bf(x.z); o.s[3] = f2bf(x.w);
    o.s[4] = f2bf(y.x); o.s[5] = f2bf(y.y); o.s[6] = f2bf(y.z); o.s[7] = f2bf(y.w);
    *(uint4*)(dst + i) = o.u;
}

// ---------------------------------------------------------------------------
// BMx128 GEMM, BK=64, bank-conflict-free (verified SQ_LDS_BANK_CONFLICT=0).
// EPI 0: fp32 C.  EPI 1: bf16 scatter to split Q/K/V.
// XCD-aware block swizzle (T1): grids are %8==0, simple bijective remap.
// ---------------------------------------------------------------------------
template <int EPI, int BM>
__global__ __launch_bounds__(256) void gemm_bt128(
    const unsigned short* __restrict__ A, const unsigned short* __restrict__ Bt,
    float* __restrict__ C,
    unsigned short* __restrict__ Qb, unsigned short* __restrict__ Kb,
    unsigned short* __restrict__ Vb, int M, int N, int K)
{
    constexpr int TM = BM / 32;                   // row-tiles per wave
    __shared__ __align__(16) short As[BM * 64];   // [row][k], swizzled granules
    __shared__ __align__(16) short Bs[128 * 64];

    const int tid = threadIdx.x;
    const int lane = tid & 63;
    const int wid = tid >> 6;
    const int quad = lane >> 4;
    const int l16 = lane & 15;

    // XCD swizzle: each XCD gets a contiguous chunk of the linear grid
    const int nwg = gridDim.x * gridDim.y;
    const int lin = blockIdx.y * gridDim.x + blockIdx.x;
    const int cpx = nwg >> 3;                      // nwg % 8 == 0 for our grids
    const int swz = (lin & 7) * cpx + (lin >> 3);
    const int bx = swz % gridDim.x;
    const int by = swz / gridDim.x;

    const int m0 = by * BM;
    const int n0 = bx * 128;
    const int wm = (wid & 1) * (BM / 2);
    const int wn = (wid >> 1) * 64;

    f32x4 acc[TM][4] = {};

    // staging: 8 lanes per row, 16B granule each; source granule pre-swizzled
    const int srow8 = lane >> 3;                  // 0..7 (row within 8-row blk)
    const int scol8 = ((lane & 7) ^ srow8) * 8;   // swizzled granule (shorts)
    const unsigned short* Ag = A + (long)(m0 + srow8) * K + scol8;
    const unsigned short* Bg = Bt + (long)(n0 + srow8) * K + scol8;
    const int gsw = l16 & 7;                      // read-side XOR key

    for (int k0 = 0; k0 < K; k0 += 64) {
        __syncthreads();
#pragma unroll
        for (int bc = 0; bc < 4; ++bc) {
            const int blk = wid + bc * 4;         // 0..15 (8-row blocks)
            if (bc < BM / 32)
                gld_lds16(Ag + (long)(blk * 8) * K + k0, &As[blk * 512]);
            gld_lds16(Bg + (long)(blk * 8) * K + k0, &Bs[blk * 512]);
        }
        __syncthreads();

#pragma unroll
        for (int ko = 0; ko < 2; ++ko) {
            const int ga = ((quad + ko * 4) ^ gsw) * 8;  // swizzled frag granule
            bf16x8 af[TM], bf[4];
#pragma unroll
            for (int t = 0; t < TM; ++t)
                af[t] = *(const bf16x8*)&As[(wm + t * 16 + l16) * 64 + ga];
#pragma unroll
            for (int t = 0; t < 4; ++t)
                bf[t] = *(const bf16x8*)&Bs[(wn + t * 16 + l16) * 64 + ga];
#pragma unroll
            for (int tm = 0; tm < TM; ++tm)
#pragma unroll
                for (int tn = 0; tn < 4; ++tn)
                    acc[tm][tn] = __builtin_amdgcn_mfma_f32_16x16x32_bf16(af[tm], bf[tn], acc[tm][tn], 0, 0, 0);
        }
    }

    if (EPI == 0) {
#pragma unroll
        for (int tm = 0; tm < TM; ++tm)
#pragma unroll
            for (int i = 0; i < 4; ++i) {
                const int row = m0 + wm + tm * 16 + quad * 4 + i;
#pragma unroll
                for (int tn = 0; tn < 4; ++tn)
                    C[(long)row * N + n0 + wn + tn * 16 + l16] = acc[tm][tn][i];
            }
    } else {
        const int slot = (n0 + wn) >> 6;  // wave-uniform: 0..47
#pragma unroll
        for (int tm = 0; tm < TM; ++tm)
#pragma unroll
            for (int i = 0; i < 4; ++i) {
                const int row = m0 + wm + tm * 16 + quad * 4 + i;
                const int b = row >> 11, s = row & 2047;
                unsigned short* base;
                if (slot < 32)      base = Qb + ((long)(b * NH + slot) * S_LEN + s) * HD;
                else if (slot < 40) base = Kb + ((long)(b * NKV + (slot - 32)) * S_LEN + s) * HD;
                else                base = Vb + ((long)(b * NKV + (slot - 40)) * S_LEN + s) * HD;
#pragma unroll
                for (int tn = 0; tn < 4; ++tn)
                    base[tn * 16 + l16] = f2bf(acc[tm][tn][i]);
            }
    }
}

// ---------------------------------------------------------------------------
// PREP kernel (fast path): three independent small jobs in ONE launch:
//   [0, 512)        V -> Vt (kv-permuted transpose)
//   [512, 10752)    LN+RoPE in-place on Q and K
//   [10752, 14848)  wo^T -> bf16 (Wot)
// ---------------------------------------------------------------------------
__global__ __launch_bounds__(256) void prep_kernel(
    const unsigned short* __restrict__ V, unsigned short* __restrict__ Vt,
    unsigned short* __restrict__ Qb, unsigned short* __restrict__ Kb,
    const float* __restrict__ qg, const float* __restrict__ qb,
    const float* __restrict__ kg, const float* __restrict__ kb,
    const float* __restrict__ fcos, const float* __restrict__ fsin,
    const float* __restrict__ wo, unsigned short* __restrict__ Wot)
{
    __shared__ __align__(16) unsigned short shbuf[64 * 72];
    const int bid = blockIdx.x;
    const int tid = threadIdx.x;

    if (bid < 512) {
        unsigned short (*tile)[72] = (unsigned short(*)[72])shbuf;
        const int bk = bid >> 5;
        const int s0 = (bid & 31) * 64;
        const int r = tid >> 2, c0 = (tid & 3) * 16;

        const unsigned short* src = V + ((long)bk * S_LEN + s0 + r) * HD + c0;
        *(uint4*)&tile[r][c0]     = *(const uint4*)src;
        *(uint4*)&tile[r][c0 + 8] = *(const uint4*)(src + 8);
        __syncthreads();

        union { uint4 u[2]; unsigned short s[16]; } o;
        const int q = tid & 3;
#pragma unroll
        for (int j = 0; j < 16; ++j) {
            const int t = 2 * (j >> 3) + ((j >> 2) & 1);
            const int kv = t * 16 + q * 4 + (j & 3);
            o.s[j] = tile[kv][r];
        }
        unsigned short* dst = Vt + ((long)bk * HD + r) * S_LEN + s0 + c0;
        *(uint4*)dst       = o.u[0];
        *(uint4*)(dst + 8) = o.u[1];
    } else if (bid < 10752) {
        const int l16 = tid & 15;
        const int rgrp = tid >> 4;
        const int row = (bid - 512) * 16 + rgrp;
        const int token = row / 40;
        const int slot = row - token * 40;
        const int b = token >> 11;
        const int s = token & 2047;
        const bool isq = slot < 32;

        unsigned short* base = isq
            ? Qb + ((long)(b * NH + slot) * S_LEN + s) * HD
            : Kb + ((long)(b * NKV + (slot - 32)) * S_LEN + s) * HD;

        union { ushort4 u; unsigned short h[4]; } in;
        in.u = *(const ushort4*)(base + l16 * 4);
        float f0 = bf2f(in.h[0]), f1 = bf2f(in.h[1]);
        float f2 = bf2f(in.h[2]), f3 = bf2f(in.h[3]);

        float sum = (f0 + f1) + (f2 + f3);
#pragma unroll
        for (int off = 1; off < 16; off <<= 1) sum += __shfl_xor(sum, off);
        const float mu = sum * (1.0f / 64.0f);
        const float d0v = f0 - mu, d1v = f1 - mu, d2v = f2 - mu, d3v = f3 - mu;
        float vs = (d0v * d0v + d1v * d1v) + (d2v * d2v + d3v * d3v);
#pragma unroll
        for (int off = 1; off < 16; off <<= 1) vs += __shfl_xor(vs, off);
        const float rs = rsqrtf(vs * (1.0f / 64.0f) + 1e-5f);

        const float4 g  = *(const float4*)((isq ? qg : kg) + l16 * 4);
        const float4 be = *(const float4*)((isq ? qb : kb) + l16 * 4);
        float n0 = d0v * rs * g.x + be.x;
        float n1 = d1v * rs * g.y + be.y;
        float n2 = d2v * rs * g.z + be.z;
        float n3 = d3v * rs * g.w + be.w;

        const float2 cs = *(const float2*)(fcos + s * 32 + l16 * 2);
        const float2 sn = *(const float2*)(fsin + s * 32 + l16 * 2);
        float o0 = n0 * cs.x - n1 * sn.x;
        float o1 = n0 * sn.x + n1 * cs.x;
        float o2 = n2 * cs.y - n3 * sn.y;
        float o3 = n2 * sn.y + n3 * cs.y;

        if (isq) { o0 *= QSCALE; o1 *= QSCALE; o2 *= QSCALE; o3 *= QSCALE; }

        union { ushort4 u; unsigned short h[4]; } out;
        out.h[0] = f2bf(o0); out.h[1] = f2bf(o1);
        out.h[2] = f2bf(o2); out.h[3] = f2bf(o3);
        *(ushort4*)(base + l16 * 4) = out.u;
    } else {
        unsigned short (*tile)[33] = (unsigned short(*)[33])shbuf;
        const int b2 = bid - 10752;
        const int bx = b2 & 63, by = b2 >> 6;
        const int tx = tid & 31;
        const int ty = tid >> 5;
        const int x = bx * 32 + tx;
        const int y0 = by * 32;
        for (int j = ty; j < 32; j += 8)
            tile[j][tx] = f2bf(wo[(long)(y0 + j) * DIMSZ + x]);
        __syncthreads();
        const int x2 = by * 32 + tx;
        const int y2 = bx * 32;
        for (int j = ty; j < 32; j += 8)
            Wot[(long)(y2 + j) * DIMSZ + x2] = tile[tx][j];
    }
}

// ---------------------------------------------------------------------------
// Fallback QKV GEMM (fp32 in, register-convert staging, 64x64).
// ---------------------------------------------------------------------------
__global__ __launch_bounds__(256) void gemm_qkv_mfma(
    const float* __restrict__ A, const float* __restrict__ Bt,
    unsigned short* __restrict__ Qb, unsigned short* __restrict__ Kb,
    unsigned short* __restrict__ Vb, int M, int N, int K)
{
    const int LW = 40;
    __shared__ __align__(16) short As[64 * LW];
    __shared__ __align__(16) short Bs[64 * LW];

    const int tid = threadIdx.x;
    const int lane = tid & 63;
    const int wid = tid >> 6;
    const int quad = lane >> 4;
    const int l16 = lane & 15;

    const int m0 = blockIdx.y * 64;
    const int n0 = blockIdx.x * 64;
    const int wm = (wid >> 1) * 32;
    const int wn = (wid & 1) * 32;

    f32x4 acc[2][2] = {};

    const int srow = tid >> 2;
    const int scol = (tid & 3) * 8;

    const float* Ag = A + (long)(m0 + srow) * K + scol;
    const float* Bg = Bt + (long)(n0 + srow) * K + scol;
    short* da = &As[srow * LW + scol];
    short* db = &Bs[srow * LW + scol];

    for (int k0 = 0; k0 < K; k0 += 32) {
        __syncthreads();
        float4 a0 = *(const float4*)(Ag + k0), a1 = *(const float4*)(Ag + k0 + 4);
        float4 b0 = *(const float4*)(Bg + k0), b1 = *(const float4*)(Bg + k0 + 4);
        union { uint4 u; short s[8]; } pa, pb;
        pa.s[0] = (short)f2bf(a0.x); pa.s[1] = (short)f2bf(a0.y);
        pa.s[2] = (short)f2bf(a0.z); pa.s[3] = (short)f2bf(a0.w);
        pa.s[4] = (short)f2bf(a1.x); pa.s[5] = (short)f2bf(a1.y);
        pa.s[6] = (short)f2bf(a1.z); pa.s[7] = (short)f2bf(a1.w);
        pb.s[0] = (short)f2bf(b0.x); pb.s[1] = (short)f2bf(b0.y);
        pb.s[2] = (short)f2bf(b0.z); pb.s[3] = (short)f2bf(b0.w);
        pb.s[4] = (short)f2bf(b1.x); pb.s[5] = (short)f2bf(b1.y);
        pb.s[6] = (short)f2bf(b1.z); pb.s[7] = (short)f2bf(b1.w);
        *(uint4*)da = pa.u;
        *(uint4*)db = pb.u;
        __syncthreads();

        bf16x8 bfr[2];
#pragma unroll
        for (int tc = 0; tc < 2; ++tc)
            bfr[tc] = *(const bf16x8*)&Bs[(wn + tc * 16 + l16) * LW + quad * 8];
#pragma unroll
        for (int tr = 0; tr < 2; ++tr) {
            bf16x8 a = *(const bf16x8*)&As[(wm + tr * 16 + l16) * LW + quad * 8];
#pragma unroll
            for (int tc = 0; tc < 2; ++tc)
                acc[tr][tc] = __builtin_amdgcn_mfma_f32_16x16x32_bf16(a, bfr[tc], acc[tr][tc], 0, 0, 0);
        }
    }

    const int slot = n0 >> 6;
#pragma unroll
    for (int tr = 0; tr < 2; ++tr)
#pragma unroll
        for (int tc = 0; tc < 2; ++tc)
#pragma unroll
            for (int i = 0; i < 4; ++i) {
                const int row = m0 + wm + tr * 16 + quad * 4 + i;
                const int d = wn + tc * 16 + l16;
                const int b = row >> 11, s = row & 2047;
                unsigned short v = f2bf(acc[tr][tc][i]);
                if (slot < 32)
                    Qb[((long)(b * NH + slot) * S_LEN + s) * HD + d] = v;
                else if (slot < 40)
                    Kb[((long)(b * NKV + (slot - 32)) * S_LEN + s) * HD + d] = v;
                else
                    Vb[((long)(b * NKV + (slot - 40)) * S_LEN + s) * HD + d] = v;
            }
}

// ---------------------------------------------------------------------------
// Fallback: in-place LayerNorm(64) + RoPE on Q and K.
// ---------------------------------------------------------------------------
__global__ __launch_bounds__(256) void lnrope_kernel(
    unsigned short* __restrict__ Qb, unsigned short* __restrict__ Kb,
    const float* __restrict__ qg, const float* __restrict__ qb,
    const float* __restrict__ kg, const float* __restrict__ kb,
    const float* __restrict__ fcos, const float* __restrict__ fsin)
{
    const int tid = threadIdx.x;
    const int l16 = tid & 15;
    const int rgrp = tid >> 4;
    const int row = blockIdx.x * 16 + rgrp;
    const int token = row / 40;
    const int slot = row - token * 40;
    const int b = token >> 11;
    const int s = token & 2047;
    const bool isq = slot < 32;

    unsigned short* base = isq
        ? Qb + ((long)(b * NH + slot) * S_LEN + s) * HD
        : Kb + ((long)(b * NKV + (slot - 32)) * S_LEN + s) * HD;

    union { ushort4 u; unsigned short h[4]; } in;
    in.u = *(const ushort4*)(base + l16 * 4);
    float f0 = bf2f(in.h[0]), f1 = bf2f(in.h[1]);
    float f2 = bf2f(in.h[2]), f3 = bf2f(in.h[3]);

    float sum = (f0 + f1) + (f2 + f3);
#pragma unroll
    for (int off = 1; off < 16; off <<= 1) sum += __shfl_xor(sum, off);
    const float mu = sum * (1.0f / 64.0f);
    const float d0v = f0 - mu, d1v = f1 - mu, d2v = f2 - mu, d3v = f3 - mu;
    float vs = (d0v * d0v + d1v * d1v) + (d2v * d2v + d3v * d3v);
#pragma unroll
    for (int off = 1; off < 16; off <<= 1) vs += __shfl_xor(vs, off);
    const float rs = rsqrtf(vs * (1.0f / 64.0f) + 1e-5f);

    const float4 g  = *(const float4*)((isq ? qg : kg) + l16 * 4);
    const float4 be = *(const float4*)((isq ? qb : kb) + l16 * 4);
    float n0 = d0v * rs * g.x + be.x;
    float n1 = d1v * rs * g.y + be.y;
    float n2 = d2v * rs * g.z + be.z;
    float n3 = d3v * rs * g.w + be.w;

    const float2 cs = *(const float2*)(fcos + s * 32 + l16 * 2);
    const float2 sn = *(const float2*)(fsin + s * 32 + l16 * 2);
    float o0 = n0 * cs.x - n1 * sn.x;
    float o1 = n0 * sn.x + n1 * cs.x;
    float o2 = n2 * cs.y - n3 * sn.y;
    float o3 = n2 * sn.y + n3 * cs.y;

    if (isq) { o0 *= QSCALE; o1 *= QSCALE; o2 *= QSCALE; o3 *= QSCALE; }

    union { ushort4 u; unsigned short h[4]; } out;
    out.h[0] = f2bf(o0); out.h[1] = f2bf(o1);
    out.h[2] = f2bf(o2); out.h[3] = f2bf(o3);
    *(ushort4*)(base + l16 * 4) = out.u;
}

// ---------------------------------------------------------------------------
// Fallback: V -> V^T in global, kv-PERMUTED within each 64-chunk.
// ---------------------------------------------------------------------------
__global__ __launch_bounds__(256) void transpose_v(
    const unsigned short* __restrict__ V, unsigned short* __restrict__ Vt)
{
    __shared__ unsigned short tile[64][72];
    const int tid = threadIdx.x;
    const int bk = blockIdx.y;
    const int s0 = blockIdx.x * 64;
    const int r = tid >> 2, c0 = (tid & 3) * 16;

    const unsigned short* src = V + ((long)bk * S_LEN + s0 + r) * HD + c0;
    *(uint4*)&tile[r][c0]     = *(const uint4*)src;
    *(uint4*)&tile[r][c0 + 8] = *(const uint4*)(src + 8);
    __syncthreads();

    union { uint4 u[2]; unsigned short s[16]; } o;
    const int q = tid & 3;
#pragma unroll
    for (int j = 0; j < 16; ++j) {
        const int t = 2 * (j >> 3) + ((j >> 2) & 1);
        const int kv = t * 16 + q * 4 + (j & 3);
        o.s[j] = tile[kv][r];
    }
    unsigned short* dst = Vt + ((long)bk * HD + r) * S_LEN + s0 + c0;
    *(uint4*)dst       = o.u[0];
    *(uint4*)(dst + 8) = o.u[1];
}

// ---------------------------------------------------------------------------
// Fallback: wo^T -> bf16, 2048x2048
// ---------------------------------------------------------------------------
__global__ __launch_bounds__(256) void transpose_wo(
    const float* __restrict__ in, unsigned short* __restrict__ out, int n)
{
    __shared__ unsigned short tile[32][33];
    const int tx = threadIdx.x & 31;
    const int ty = threadIdx.x >> 5;
    const int x = blockIdx.x * 32 + tx;
    const int y0 = blockIdx.y * 32;
    for (int j = ty; j < 32; j += 8) tile[j][tx] = f2bf(in[(long)(y0 + j) * n + x]);
    __syncthreads();
    const int x2 = blockIdx.y * 32 + tx;
    const int y2 = blockIdx.x * 32;
    for (int j = ty; j < 32; j += 8) out[(long)(y2 + j) * n + x2] = tile[tx][j];
}

// ---------------------------------------------------------------------------
// MFMA flash attention, causal. Triangle-paired, 8-wave blocks.
// STRIP-INTERLEAVED work assignment (round 15): every wave owns ONE 16-row
// strip of the tlo tile (base0 = tlo*128 + wid*16, subtile 0) and ONE of
// the thi tile (base1 = thi*128 + wid*16, subtile 1).  Early chunks: 2
// subtiles/wave (same as before).  Late chunks (tlo strips done): all 8
// waves carry 1 subtile each instead of 4 waves carrying 2 -> per-chunk
// critical path halves where most chunks live.  Staging/barriers/softmax
// unchanged (round-11 verified).
// ---------------------------------------------------------------------------
#define KSTR 72  // LDS stride (shorts)

__global__ __launch_bounds__(512, 4) void attn_mfma(
    const unsigned short* __restrict__ Q,
    const unsigned short* __restrict__ Kin,
    const unsigned short* __restrict__ Vtg,
    unsigned short* __restrict__ Oatt)
{
    __shared__ __align__(16) short Ks[2][64 * KSTR];   // [buf][kv][hd]
    __shared__ __align__(16) short Vs[2][64 * KSTR];   // [buf][d][kv-perm]

    const int tid = threadIdx.x;
    const int lane = tid & 63;
    const int wid = tid >> 6;          // 0..7
    const int quad = lane >> 4;
    const int l16 = lane & 15;

    const int bh = blockIdx.x;
    const int b = bh >> 5, h = bh & 31, kvh = h >> 2;
    const int NY = S_LEN / 128;                 // 16 q-tiles
    const int tlo = blockIdx.y;                 // 0..7
    const int thi = (NY - 1) - tlo;             // 15..8
    const int base0 = tlo * 128 + wid * 16;     // subtile 0: strip of tlo
    const int base1 = thi * 128 + wid * 16;     // subtile 1: strip of thi

    const unsigned short* Qb = Q + (long)(b * NH + h) * S_LEN * HD;
    const unsigned short* Kb = Kin + (long)(b * NKV + kvh) * S_LEN * HD;
    const unsigned short* Vtb = Vtg + (long)(b * NKV + kvh) * HD * S_LEN;

    bf16x8 qf[2][2];  // [sub][half]
    qf[0][0] = *(const bf16x8*)(Qb + (long)(base0 + l16) * HD + quad * 8);
    qf[0][1] = *(const bf16x8*)(Qb + (long)(base0 + l16) * HD + 32 + quad * 8);
    qf[1][0] = *(const bf16x8*)(Qb + (long)(base1 + l16) * HD + quad * 8);
    qf[1][1] = *(const bf16x8*)(Qb + (long)(base1 + l16) * HD + 32 + quad * 8);

    f32x4 oacc[2][4] = {};
    float l_r[2] = {0.0f, 0.0f};   // per-lane partial denominators

    // staging: tid<256 -> K, tid>=256 -> V; 32B per thread
    const bool stK = tid < 256;
    const int st = stK ? tid : tid - 256;
    const int kk = st >> 2;           // row (K: kv row, V: d row)
    const int d0 = (st & 3) * 16;     // 16-short segment
    const unsigned short* gsrc = stK
        ? Kb + (long)kk * HD + d0
        : Vtb + (long)kk * S_LEN + d0;
    const long ginc = stK ? (long)64 * HD : 64;  // per-chunk advance (shorts)
    short* const lds0 = stK ? &Ks[0][kk * KSTR + d0] : &Vs[0][kk * KSTR + d0];
    short* const lds1 = stK ? &Ks[1][kk * KSTR + d0] : &Vs[1][kk * KSTR + d0];

    const int nch = 2 * thi + 2;      // hi tile defines the chunk range

    uint4 r0, r1;
    {   // prologue: chunk 0 -> regs -> buf0
        r0 = *(const uint4*)gsrc; r1 = *(const uint4*)(gsrc + 8);
        *(uint4*)lds0 = r0; *(uint4*)(lds0 + 8) = r1;
    }

    for (int c = 0; c < nch; ++c) {
        const int cur = c & 1;
        const int kbase = c * 64;
        __syncthreads();  // buf[cur] ready; all waves done reading buf[cur^1]

        // issue loads for chunk c+1 (latency hides under compute of chunk c)
        if (c + 1 < nch) {
            const unsigned short* p = gsrc + (long)(c + 1) * ginc;
            r0 = *(const uint4*)p; r1 = *(const uint4*)(p + 8);
        }

        if (kbase <= base1 + 15) {    // subtile 1 (thi strip) still active?
            const bool act0 = (kbase <= base0 + 15);  // subtile 0 active?
            const short* Ksc = Ks[cur];
            const short* Vsc = Vs[cur];

            // ---- QK^T swapped, K-frags read once, shared by both subtiles:
            //      sc[s][t][r] = S[kv=kbase+16t+4*quad+r][q=base_s+l16]
            f32x4 sc[2][4];
            __builtin_amdgcn_s_setprio(1);
#pragma unroll
            for (int t = 0; t < 4; ++t) {
                bf16x8 kf0 = *(const bf16x8*)&Ksc[(t * 16 + l16) * KSTR + quad * 8];
                bf16x8 kf1 = *(const bf16x8*)&Ksc[(t * 16 + l16) * KSTR + 32 + quad * 8];
#pragma unroll
                for (int s = 0; s < 2; ++s) {
                    if (s == 0 && !act0) continue;
                    f32x4 z = {};
                    z = __builtin_amdgcn_mfma_f32_16x16x32_bf16(kf0, qf[s][0], z, 0, 0, 0);
                    sc[s][t] = __builtin_amdgcn_mfma_f32_16x16x32_bf16(kf1, qf[s][1], z, 0, 0, 0);
                }
            }
            __builtin_amdgcn_s_setprio(0);

#pragma unroll
            for (int s = 0; s < 2; ++s) {
                if (s == 0 && !act0) continue;
                const int qw = s ? base1 : base0;
                const bool diag = (kbase + 63 > qw);  // wave-uniform

                // ---- mask in place (diag only); exp2(-1e30) == 0 ----
                if (diag) {
                    const int rel = qw + l16 - kbase;
#pragma unroll
                    for (int t = 0; t < 4; ++t)
#pragma unroll
                        for (int r = 0; r < 4; ++r) {
                            const int kvrel = t * 16 + quad * 4 + r;
                            if (kvrel > rel) sc[s][t][r] = -1e30f;
                        }
                }

                // ---- raw exp2 (shift-invariant softmax), per-lane partial sum
                float sum = 0.0f;
#pragma unroll
                for (int t = 0; t < 4; ++t)
#pragma unroll
                    for (int r = 0; r < 4; ++r) {
                        sc[s][t][r] = exp2_fast(sc[s][t][r]);
                        sum += sc[s][t][r];
                    }
                l_r[s] += sum;

                // ---- pack P: k-slot quad*8+j -> kv = 16*t(j)+4*quad+(j&3) ----
                union { bf16x8 v8; unsigned int w[4]; } pf01, pf23;
                pf01.w[0] = cvt_pk_bf16(sc[s][0][0], sc[s][0][1]);
                pf01.w[1] = cvt_pk_bf16(sc[s][0][2], sc[s][0][3]);
                pf01.w[2] = cvt_pk_bf16(sc[s][1][0], sc[s][1][1]);
                pf01.w[3] = cvt_pk_bf16(sc[s][1][2], sc[s][1][3]);
                pf23.w[0] = cvt_pk_bf16(sc[s][2][0], sc[s][2][1]);
                pf23.w[1] = cvt_pk_bf16(sc[s][2][2], sc[s][2][3]);
                pf23.w[2] = cvt_pk_bf16(sc[s][3][0], sc[s][3][1]);
                pf23.w[3] = cvt_pk_bf16(sc[s][3][2], sc[s][3][3]);

                // ---- PV: V kv-permuted -> both B-frags are b128 reads ----
                __builtin_amdgcn_s_setprio(1);
#pragma unroll
                for (int dt = 0; dt < 4; ++dt) {
                    const short* vb = &Vsc[(dt * 16 + l16) * KSTR + quad * 16];
                    bf16x8 vf01 = *(const bf16x8*)(vb);
                    bf16x8 vf23 = *(const bf16x8*)(vb + 8);
                    oacc[s][dt] = __builtin_amdgcn_mfma_f32_16x16x32_bf16(pf01.v8, vf01, oacc[s][dt], 0, 0, 0);
                    oacc[s][dt] = __builtin_amdgcn_mfma_f32_16x16x32_bf16(pf23.v8, vf23, oacc[s][dt], 0, 0, 0);
                }
                __builtin_amdgcn_s_setprio(0);
            }
        }

        // write chunk c+1 into the other buffer
        if (c + 1 < nch) {
            short* d = cur ? lds0 : lds1;
            *(uint4*)d = r0; *(uint4*)(d + 8) = r1;
        }
    }

#pragma unroll
    for (int s = 0; s < 2; ++s) {
        float tot = l_r[s];
        tot += __shfl_xor(tot, 16);
        tot += __shfl_xor(tot, 32);
        const float linv = 1.0f / tot;  // at q = base_s + l16
        const int bs = s ? base1 : base0;
#pragma unroll
        for (int r = 0; r < 4; ++r) {
            const float inv = __shfl(linv, quad * 4 + r, 16);
            const int qabs = bs + quad * 4 + r;
            unsigned short* op = Oatt + (long)(b * S_LEN + qabs) * DIMSZ + h * HD;
#pragma unroll
            for (int dt = 0; dt < 4; ++dt)
                op[dt * 16 + l16] = f2bf(oacc[s][dt][r] * inv);
        }
    }
}

// ---------------------------------------------------------------------------
extern "C" void kernel_launch(void* const* d_in, const int* in_sizes, int n_in,
                              void* d_out, int out_size, void* d_ws, size_t ws_size,
                              hipStream_t stream)
{
    const float* x    = (const float*)d_in[0];
    const float* wqkv = (const float*)d_in[1];
    const float* wo   = (const float*)d_in[2];
    const float* qg   = (const float*)d_in[3];
    const float* qb   = (const float*)d_in[4];
    const float* kg   = (const float*)d_in[5];
    const float* kb   = (const float*)d_in[6];
    const float* fc   = (const float*)d_in[7];
    const float* fs   = (const float*)d_in[8];
    // d_in[9] = mask: tril(NEG) — applied analytically

    char* ws = (char*)d_ws;
    // fast layout (bytes):
    // [0,        16777216)  Q bf16
    // [16777216, 20971520)  K bf16
    // [20971520, 25165824)  V bf16
    // [25165824, 41943040)  Oatt bf16         (x16 overlay during phase 1)
    // [41943040, 46137344)  Vt bf16           (w16 overlay during phase 1)
    // [46137344, 54525952)  Wot bf16          (w16 tail; free after QKV GEMM)
    unsigned short* Qr   = (unsigned short*)ws;
    unsigned short* Kr   = (unsigned short*)(ws + 16777216);
    unsigned short* Vr   = (unsigned short*)(ws + 20971520);
    unsigned short* Oatt = (unsigned short*)(ws + 25165824);
    unsigned short* x16  = (unsigned short*)(ws + 25165824);
    unsigned short* w16  = (unsigned short*)(ws + 41943040);
    unsigned short* Vt   = (unsigned short*)(ws + 41943040);
    unsigned short* WotF = (unsigned short*)(ws + 46137344);  // fast path
    unsigned short* Wot0 = (unsigned short*)ws;               // fallback (dead Q)

    dim3 blk(256);
    const bool fast = ws_size >= 54525952ull;

    if (fast) {
        convert_bf16_2<<<dim3(4096 + 3072), blk, 0, stream>>>(x, x16, wqkv, w16, 4096);
        gemm_bt128<1, 128><<<dim3(QKV_N / 128, NTOK / 128), blk, 0, stream>>>(
            x16, w16, nullptr, Qr, Kr, Vr, NTOK, QKV_N, DIMSZ);
        // V->Vt + LN/RoPE + wo^T in ONE launch (block-range dispatch)
        prep_kernel<<<dim3(512 + 10240 + 4096), blk, 0, stream>>>(
            Vr, Vt, Qr, Kr, qg, qb, kg, kb, fc, fs, wo, WotF);
        attn_mfma<<<dim3(NBATCH * NH, S_LEN / 256), dim3(512), 0, stream>>>(
            Qr, Kr, Vt, Oatt);
        gemm_bt128<0, 64><<<dim3(DIMSZ / 128, NTOK / 64), blk, 0, stream>>>(
            Oatt, WotF, (float*)d_out, nullptr, nullptr, nullptr, NTOK, DIMSZ, DIMSZ);
    } else {
        gemm_qkv_mfma<<<dim3(QKV_N / 64, NTOK / 64), blk, 0, stream>>>(
            x, wqkv, Qr, Kr, Vr, NTOK, QKV_N, DIMSZ);
        transpose_v<<<dim3(S_LEN / 64, NBATCH * NKV), blk, 0, stream>>>(Vr, Vt);
        lnrope_kernel<<<dim3(NTOK * 40 / 16), blk, 0, stream>>>(
            Qr, Kr, qg, qb, kg, kb, fc, fs);
        attn_mfma<<<dim3(NBATCH * NH, S_LEN / 256), dim3(512), 0, stream>>>(
            Qr, Kr, Vt, Oatt);
        transpose_wo<<<dim3(64, 64), blk, 0, stream>>>(wo, Wot0, DIMSZ);
        gemm_bt128<0, 64><<<dim3(DIMSZ / 128, NTOK / 64), blk, 0, stream>>>(
            Oatt, Wot0, (float*)d_out, nullptr, nullptr, nullptr, NTOK, DIMSZ, DIMSZ);
    }
}